// Round 1
// baseline (921.391 us; speedup 1.0000x reference)
//
#include <hip/hip_runtime.h>
#include <hip/hip_bf16.h>
#include <stdint.h>

#define G 256
#define NPG 400
#define DEG 32
#define FIN 400
#define H 64
#define NN (G*NPG)        // 102400
#define EE (G*NPG*DEG)    // 3276800
#define EPG (NPG*DEG)     // 12800 edges per graph
#define CPG (EPG+NPG)     // 13200 CSR entries per graph (edges + self loops)

// ---------------- K0: degree, dinv, per-graph CSR build ----------------
__global__ __launch_bounds__(256) void k0_build(
    const int* __restrict__ ei,       // [2*EE] rows then cols
    const float* __restrict__ ew,     // [EE]
    uint2* __restrict__ csr,          // [G*CPG]  {row_local, norm_bits}
    uint32_t* __restrict__ noff)      // [NN+1]
{
  __shared__ uint32_t cnt[NPG];
  __shared__ float    deg[NPG];
  __shared__ float    dv[NPG];
  __shared__ uint32_t offs[NPG+1];
  __shared__ uint32_t woff[NPG];
  const int g = blockIdx.x;
  const int tid = threadIdx.x;
  const int ebase = g*EPG;
  const int nbase = g*NPG;
  const int cbase = g*CPG;
  const int* rowp = ei;
  const int* colp = ei + EE;

  for (int v = tid; v < NPG; v += 256) { cnt[v] = 0u; deg[v] = 1.0f; }
  __syncthreads();
  for (int e = tid; e < EPG; e += 256) {
    int c = colp[ebase+e] - nbase;
    atomicAdd(&cnt[c], 1u);
    atomicAdd(&deg[c], ew[ebase+e]);
  }
  __syncthreads();
  for (int v = tid; v < NPG; v += 256) {
    float d = deg[v];
    dv[v] = (d > 0.f) ? rsqrtf(d) : 0.f;
  }
  __syncthreads();
  // exclusive scan of (cnt[v]+1) over 400 nodes, wave 0 only
  if (tid < 64) {
    int base = tid*7;
    uint32_t loc[7]; uint32_t s = 0;
    #pragma unroll
    for (int j = 0; j < 7; ++j) {
      int idx = base + j;
      uint32_t val = (idx < NPG) ? (cnt[idx] + 1u) : 0u;
      loc[j] = s; s += val;
    }
    uint32_t run = s;
    #pragma unroll
    for (int o = 1; o < 64; o <<= 1) {
      uint32_t t = __shfl_up(run, o);
      if (tid >= o) run += t;
    }
    uint32_t excl = run - s;
    #pragma unroll
    for (int j = 0; j < 7; ++j) {
      int idx = base + j;
      if (idx < NPG) offs[idx] = excl + loc[j];
    }
    if (tid == 63) offs[NPG] = excl + s;
  }
  __syncthreads();
  // self-loop entry first per node; init working offsets; global node offsets
  for (int v = tid; v < NPG; v += 256) {
    uint32_t o = offs[v];
    woff[v] = o + 1u;
    float d = dv[v];
    csr[cbase + o] = make_uint2((uint32_t)v, __float_as_uint(d*d));
    noff[nbase + v] = (uint32_t)(cbase + o);
  }
  if (g == G-1 && tid == 0) noff[NN] = (uint32_t)(G*CPG);
  __syncthreads();
  // place edges
  for (int e = tid; e < EPG; e += 256) {
    int r = rowp[ebase+e] - nbase;
    int c = colp[ebase+e] - nbase;
    float w = ew[ebase+e];
    float nm = dv[r] * w * dv[c];
    uint32_t pos = atomicAdd(&woff[c], 1u);
    csr[cbase + pos] = make_uint2((uint32_t)r, __float_as_uint(nm));
  }
}

// ---------------- K1: m1 = x @ W1  (102400x400 @ 400x64, fp32) ----------------
// W1^T staged in LDS (stride 404 floats -> 16B aligned, all banks covered).
// Each wave: groups of 8 rows, broadcast float4 x loads, 1 ds_read_b128 per 4k.
__global__ __launch_bounds__(1024) void k1_gemm1(
    const float* __restrict__ x, const float* __restrict__ W1,
    float* __restrict__ m1)
{
  extern __shared__ float sW[];   // 64 * 404 floats
  const int tid = threadIdx.x;
  for (int i = tid; i < FIN*H; i += 1024) {
    int k = i >> 6, f = i & 63;
    sW[f*404 + k] = W1[i];
  }
  __syncthreads();
  const int lane = tid & 63, wave = tid >> 6;
  const int rbase = blockIdx.x * NPG;
  for (int gi = wave; gi < 50; gi += 16) {
    const int r0 = rbase + gi*8;
    const float* xp = x + (size_t)r0 * FIN;
    float acc[8] = {0,0,0,0,0,0,0,0};
    const float* wl = &sW[lane*404];
    for (int kb = 0; kb < FIN; kb += 4) {
      float4 w4 = *(const float4*)(wl + kb);
      #pragma unroll
      for (int r = 0; r < 8; ++r) {
        float4 x4 = *(const float4*)(xp + r*FIN + kb);
        acc[r] += x4.x*w4.x + x4.y*w4.y + x4.z*w4.z + x4.w*w4.w;
      }
    }
    #pragma unroll
    for (int r = 0; r < 8; ++r)
      m1[(size_t)(r0 + r)*H + lane] = acc[r];
  }
}

// ---------------- K2/K3/K4: per-graph [GEMM +] scatter-aggregate ----------------
// LOAD_M=1: m tile copied from global (layer 1). LOAD_M=0: m = h_in @ W in-block.
// Scatter: 4 CSR entries per wave iteration, 16 lanes x float4 per entry,
// cross-group shfl_xor reduce, bias + optional relu.
template<int LOAD_M, int RELU>
__global__ __launch_bounds__(1024) void k_layer(
    const float* __restrict__ min_or_h,
    const float* __restrict__ W,       // 64x64 (unused if LOAD_M)
    const float* __restrict__ bias,    // 64
    const uint2* __restrict__ csr,
    const uint32_t* __restrict__ noff,
    float* __restrict__ hout)
{
  extern __shared__ float smem[];
  float* mt  = smem;                // 400*64
  float* sWT = smem + NPG*H;        // 64*68 (only if !LOAD_M)
  const int tid = threadIdx.x, lane = tid & 63, wave = tid >> 6;
  const int g = blockIdx.x, nbase = g*NPG;

  if (LOAD_M) {
    const float4* src = (const float4*)(min_or_h + (size_t)nbase*H);
    float4* dst = (float4*)mt;
    for (int i = tid; i < NPG*H/4; i += 1024) dst[i] = src[i];
  } else {
    for (int i = tid; i < H*H; i += 1024) {
      int k = i >> 6, f = i & 63;
      sWT[f*68 + k] = W[i];
    }
    __syncthreads();
    for (int gi = wave; gi < 50; gi += 16) {
      const float* hp = min_or_h + (size_t)(nbase + gi*8)*H;
      float acc[8] = {0,0,0,0,0,0,0,0};
      const float* wl = &sWT[lane*68];
      for (int kb = 0; kb < H; kb += 4) {
        float4 w4 = *(const float4*)(wl + kb);
        #pragma unroll
        for (int r = 0; r < 8; ++r) {
          float4 h4 = *(const float4*)(hp + r*H + kb);
          acc[r] += h4.x*w4.x + h4.y*w4.y + h4.z*w4.z + h4.w*w4.w;
        }
      }
      #pragma unroll
      for (int r = 0; r < 8; ++r)
        mt[(gi*8 + r)*H + lane] = acc[r];
    }
  }
  __syncthreads();

  const uint32_t grp = (uint32_t)(lane >> 4);
  const int fq = lane & 15;
  for (int v = wave; v < NPG; v += 16) {
    const uint32_t s = noff[nbase + v], e = noff[nbase + v + 1];
    float4 acc = make_float4(0.f, 0.f, 0.f, 0.f);
    uint32_t i = s;
    for (; i + 4 <= e; i += 4) {
      uint2 E0 = csr[i+0], E1 = csr[i+1], E2 = csr[i+2], E3 = csr[i+3];
      uint2 Eg = (grp == 0u) ? E0 : (grp == 1u) ? E1 : (grp == 2u) ? E2 : E3;
      float nm = __uint_as_float(Eg.y);
      float4 mv = *(const float4*)&mt[Eg.x*H + fq*4];
      acc.x += nm*mv.x; acc.y += nm*mv.y; acc.z += nm*mv.z; acc.w += nm*mv.w;
    }
    if (i + grp < e) {
      uint2 Eg = csr[i + grp];
      float nm = __uint_as_float(Eg.y);
      float4 mv = *(const float4*)&mt[Eg.x*H + fq*4];
      acc.x += nm*mv.x; acc.y += nm*mv.y; acc.z += nm*mv.z; acc.w += nm*mv.w;
    }
    #pragma unroll
    for (int d = 16; d <= 32; d <<= 1) {
      acc.x += __shfl_xor(acc.x, d);
      acc.y += __shfl_xor(acc.y, d);
      acc.z += __shfl_xor(acc.z, d);
      acc.w += __shfl_xor(acc.w, d);
    }
    if (lane < 16) {
      float4 b4 = *(const float4*)&bias[lane*4];
      float4 r;
      r.x = acc.x + b4.x; r.y = acc.y + b4.y;
      r.z = acc.z + b4.z; r.w = acc.w + b4.w;
      if (RELU) {
        r.x = fmaxf(r.x, 0.f); r.y = fmaxf(r.y, 0.f);
        r.z = fmaxf(r.z, 0.f); r.w = fmaxf(r.w, 0.f);
      }
      *(float4*)&hout[(size_t)(nbase + v)*H + lane*4] = r;
    }
  }
}

// ---------------- K5: readout partial  g += h3(64 graphs) x Wc(4 nodes) ----------
__global__ __launch_bounds__(1024) void k5_readout(
    const float* __restrict__ h3, const float* __restrict__ Wc,
    float* __restrict__ gbuf)
{
  extern __shared__ float smem[];
  float* swc = smem;            // 256*64
  float* sh  = smem + 256*64;   // 64 * 260 (pad 4)
  const int tid = threadIdx.x;
  const int vc = blockIdx.x % 100, gg = blockIdx.x / 100;
  const int v0 = vc*4, g0 = gg*64;

  const float4* wsrc = (const float4*)(Wc + (size_t)v0*64*64);
  float4* wdst = (float4*)swc;
  for (int i = tid; i < (256*64)/4; i += 1024) wdst[i] = wsrc[i];
  for (int i = tid; i < 64*256; i += 1024) {
    int j = i >> 8, rest = i & 255;
    int v = rest >> 6, k = rest & 63;
    sh[j*260 + rest] = h3[((size_t)(g0 + j)*NPG + v0 + v)*H + k];
  }
  __syncthreads();

  const int gr = tid >> 4, fq = tid & 15;
  float4 acc = make_float4(0.f, 0.f, 0.f, 0.f);
  const float* shp = &sh[gr*260];
  for (int t = 0; t < 256; ++t) {
    float hv = shp[t];
    float4 w4 = *(const float4*)&swc[t*64 + fq*4];
    acc.x += hv*w4.x; acc.y += hv*w4.y; acc.z += hv*w4.z; acc.w += hv*w4.w;
  }
  float* gp = gbuf + (size_t)(g0 + gr)*H + fq*4;
  atomicAdd(gp+0, acc.x); atomicAdd(gp+1, acc.y);
  atomicAdd(gp+2, acc.z); atomicAdd(gp+3, acc.w);
}

// ---------------- K6: out = (g + bc) @ Wl + bl ----------------
__global__ __launch_bounds__(512) void k6_final(
    const float* __restrict__ gbuf, const float* __restrict__ bc,
    const float* __restrict__ Wl, const float* __restrict__ bl,
    float* __restrict__ out)
{
  int t = threadIdx.x;           // 512 = 256 graphs * 2 outputs
  int gr = t >> 1, c = t & 1;
  float acc = bl[c];
  for (int f = 0; f < H; ++f)
    acc += (gbuf[gr*H + f] + bc[f]) * Wl[f*2 + c];
  out[gr*2 + c] = acc;
}

extern "C" void kernel_launch(void* const* d_in, const int* in_sizes, int n_in,
                              void* d_out, int out_size, void* d_ws, size_t ws_size,
                              hipStream_t stream)
{
  const float* x  = (const float*)d_in[0];
  const int*   ei = (const int*)d_in[1];
  const float* ew = (const float*)d_in[2];
  const float* W1 = (const float*)d_in[3];
  const float* b1 = (const float*)d_in[4];
  const float* W2 = (const float*)d_in[5];
  const float* b2 = (const float*)d_in[6];
  const float* W3 = (const float*)d_in[7];
  const float* b3 = (const float*)d_in[8];
  const float* Wc = (const float*)d_in[9];
  const float* bc = (const float*)d_in[10];
  const float* Wl = (const float*)d_in[11];
  const float* bl = (const float*)d_in[12];
  float* out = (float*)d_out;

  char* ws = (char*)d_ws;
  size_t o = 0;
  float*    A    = (float*)(ws + o);    o += (size_t)NN*H*4;        // 26.2 MB
  float*    B    = (float*)(ws + o);    o += (size_t)NN*H*4;        // 26.2 MB
  uint2*    csr  = (uint2*)(ws + o);    o += (size_t)G*CPG*8;       // 27.0 MB
  uint32_t* noff = (uint32_t*)(ws + o); o += ((size_t)NN + 4)*4;    // 0.4 MB
  float*    gbuf = (float*)(ws + o);    o += (size_t)G*H*4;         // 64 KB

  hipMemsetAsync(gbuf, 0, (size_t)G*H*4, stream);

  k0_build<<<G, 256, 0, stream>>>(ei, ew, csr, noff);
  k1_gemm1<<<G, 1024, 64*404*4, stream>>>(x, W1, A);
  k_layer<1,1><<<G, 1024, NPG*H*4, stream>>>(A, nullptr, b1, csr, noff, B);
  k_layer<0,1><<<G, 1024, (NPG*H + 64*68)*4, stream>>>(B, W2, b2, csr, noff, A);
  k_layer<0,0><<<G, 1024, (NPG*H + 64*68)*4, stream>>>(A, W3, b3, csr, noff, B);
  k5_readout<<<400, 1024, (256*64 + 64*260)*4, stream>>>(B, Wc, gbuf);
  k6_final<<<1, 512, 0, stream>>>(gbuf, bc, Wl, bl, out);
}

// Round 2
// 633.559 us; speedup vs baseline: 1.4543x; 1.4543x over previous
//
#include <hip/hip_runtime.h>
#include <hip/hip_bf16.h>
#include <stdint.h>

#define G 256
#define NPG 400
#define DEG 32
#define FIN 400
#define H 64
#define NN (G*NPG)        // 102400
#define EE (G*NPG*DEG)    // 3276800
#define EPG (NPG*DEG)     // 12800 edges per graph
#define CPG (EPG+NPG)     // 13200 CSR entries per graph (edges + self loops)

typedef __attribute__((ext_vector_type(8))) short bf16x8;
typedef __attribute__((ext_vector_type(4))) float f32x4;

static __device__ __forceinline__ unsigned short f2bf(float f) {
  unsigned u = __float_as_uint(f);
  unsigned r = (u + 0x7fffu + ((u >> 16) & 1u)) >> 16;   // RNE
  return (unsigned short)r;
}

// ---------------- K0: degree, dinv, per-graph CSR build ----------------
__global__ __launch_bounds__(256) void k0_build(
    const int* __restrict__ ei,       // [2*EE] rows then cols
    const float* __restrict__ ew,     // [EE]
    uint2* __restrict__ csr,          // [G*CPG]  {row_local, norm_bits}
    uint32_t* __restrict__ noff)      // [NN+1]
{
  __shared__ uint32_t cnt[NPG];
  __shared__ float    deg[NPG];
  __shared__ float    dv[NPG];
  __shared__ uint32_t offs[NPG+1];
  __shared__ uint32_t woff[NPG];
  const int g = blockIdx.x;
  const int tid = threadIdx.x;
  const int ebase = g*EPG;
  const int nbase = g*NPG;
  const int cbase = g*CPG;
  const int* rowp = ei;
  const int* colp = ei + EE;

  for (int v = tid; v < NPG; v += 256) { cnt[v] = 0u; deg[v] = 1.0f; }
  __syncthreads();
  for (int e = tid; e < EPG; e += 256) {
    int c = colp[ebase+e] - nbase;
    atomicAdd(&cnt[c], 1u);
    atomicAdd(&deg[c], ew[ebase+e]);
  }
  __syncthreads();
  for (int v = tid; v < NPG; v += 256) {
    float d = deg[v];
    dv[v] = (d > 0.f) ? rsqrtf(d) : 0.f;
  }
  __syncthreads();
  // exclusive scan of (cnt[v]+1) over 400 nodes, wave 0 only
  if (tid < 64) {
    int base = tid*7;
    uint32_t loc[7]; uint32_t s = 0;
    #pragma unroll
    for (int j = 0; j < 7; ++j) {
      int idx = base + j;
      uint32_t val = (idx < NPG) ? (cnt[idx] + 1u) : 0u;
      loc[j] = s; s += val;
    }
    uint32_t run = s;
    #pragma unroll
    for (int o = 1; o < 64; o <<= 1) {
      uint32_t t = __shfl_up(run, o);
      if (tid >= o) run += t;
    }
    uint32_t excl = run - s;
    #pragma unroll
    for (int j = 0; j < 7; ++j) {
      int idx = base + j;
      if (idx < NPG) offs[idx] = excl + loc[j];
    }
    if (tid == 63) offs[NPG] = excl + s;
  }
  __syncthreads();
  for (int v = tid; v < NPG; v += 256) {
    uint32_t o = offs[v];
    woff[v] = o + 1u;
    float d = dv[v];
    csr[cbase + o] = make_uint2((uint32_t)v, __float_as_uint(d*d));
    noff[nbase + v] = (uint32_t)(cbase + o);
  }
  if (g == G-1 && tid == 0) noff[NN] = (uint32_t)(G*CPG);
  __syncthreads();
  for (int e = tid; e < EPG; e += 256) {
    int r = rowp[ebase+e] - nbase;
    int c = colp[ebase+e] - nbase;
    float w = ew[ebase+e];
    float nm = dv[r] * w * dv[c];
    uint32_t pos = atomicAdd(&woff[c], 1u);
    csr[cbase + pos] = make_uint2((uint32_t)r, __float_as_uint(nm));
  }
}

// ---------------- KW: pack W1 into MFMA B-fragment order, hi/lo bf16 ----------
// Layout: frag[ks][nt][lane][j], ks=0..12 (K padded 400->416), nt=0..3,
// element = W[k][col], k = ks*32 + (lane>>4)*8 + j, col = nt*16 + (lane&15).
__global__ __launch_bounds__(256) void kW_frag(
    const float* __restrict__ W,
    unsigned short* __restrict__ wfh, unsigned short* __restrict__ wfl)
{
  int idx = blockIdx.x*256 + threadIdx.x;     // 0..26623
  if (idx >= 13*4*64*8) return;
  int j    = idx & 7;
  int lane = (idx >> 3) & 63;
  int nt   = (idx >> 9) & 3;
  int ks   = idx >> 11;
  int k    = ks*32 + (lane >> 4)*8 + j;
  int col  = nt*16 + (lane & 15);
  float v = (k < FIN) ? W[k*H + col] : 0.f;
  unsigned short hi = f2bf(v);
  float fh = __uint_as_float((unsigned)hi << 16);
  unsigned short lo = f2bf(v - fh);
  wfh[idx] = hi;
  wfl[idx] = lo;
}

// ---------------- K1: m1 = x @ W1 via MFMA, hi/lo 3-pass (fp32-accurate) -----
// No LDS, no barriers. Wave = 16 rows x 64 cols. 1600 blocks x 256 thr.
__global__ __launch_bounds__(256) void k1_mfma(
    const float* __restrict__ x,
    const unsigned short* __restrict__ wfh,
    const unsigned short* __restrict__ wfl,
    float* __restrict__ m1)
{
  const int tid = threadIdx.x, lane = tid & 63, wave = tid >> 6;
  const int mrow = blockIdx.x*64 + wave*16;
  const int arow = mrow + (lane & 15);
  const int kgrp = lane >> 4;
  f32x4 acc[4] = {{0,0,0,0},{0,0,0,0},{0,0,0,0},{0,0,0,0}};
  const float* xp = x + (size_t)arow*FIN;

  for (int ks = 0; ks < 13; ++ks) {
    const int kbase = ks*32 + kgrp*8;
    float xv[8];
    if (kbase + 8 <= FIN) {
      float4 a0 = *(const float4*)(xp + kbase);
      float4 a1 = *(const float4*)(xp + kbase + 4);
      xv[0]=a0.x; xv[1]=a0.y; xv[2]=a0.z; xv[3]=a0.w;
      xv[4]=a1.x; xv[5]=a1.y; xv[6]=a1.z; xv[7]=a1.w;
    } else {
      #pragma unroll
      for (int j = 0; j < 8; ++j) xv[j] = 0.f;
    }
    bf16x8 ahi, alo;
    #pragma unroll
    for (int j = 0; j < 8; ++j) {
      unsigned short h = f2bf(xv[j]);
      float fh = __uint_as_float((unsigned)h << 16);
      unsigned short l = f2bf(xv[j] - fh);
      ahi[j] = (short)h;
      alo[j] = (short)l;
    }
    #pragma unroll
    for (int nt = 0; nt < 4; ++nt) {
      const size_t fb = (((size_t)(ks*4 + nt))*64 + lane)*8;
      bf16x8 bhi = *(const bf16x8*)(wfh + fb);
      bf16x8 blo = *(const bf16x8*)(wfl + fb);
      acc[nt] = __builtin_amdgcn_mfma_f32_16x16x32_bf16(ahi, bhi, acc[nt], 0, 0, 0);
      acc[nt] = __builtin_amdgcn_mfma_f32_16x16x32_bf16(alo, bhi, acc[nt], 0, 0, 0);
      acc[nt] = __builtin_amdgcn_mfma_f32_16x16x32_bf16(ahi, blo, acc[nt], 0, 0, 0);
    }
  }
  // D layout: row = (lane>>4)*4 + r, col = nt*16 + (lane&15)
  #pragma unroll
  for (int nt = 0; nt < 4; ++nt) {
    #pragma unroll
    for (int r = 0; r < 4; ++r) {
      m1[(size_t)(mrow + kgrp*4 + r)*H + nt*16 + (lane & 15)] = acc[nt][r];
    }
  }
}

// ---------------- K2/K3/K4: per-graph [GEMM +] scatter-aggregate ----------------
template<int LOAD_M, int RELU>
__global__ __launch_bounds__(1024) void k_layer(
    const float* __restrict__ min_or_h,
    const float* __restrict__ W,       // 64x64 (unused if LOAD_M)
    const float* __restrict__ bias,    // 64
    const uint2* __restrict__ csr,
    const uint32_t* __restrict__ noff,
    float* __restrict__ hout)
{
  extern __shared__ float smem[];
  float* mt  = smem;                // 400*64
  float* sWT = smem + NPG*H;        // 64*68 (only if !LOAD_M)
  const int tid = threadIdx.x, lane = tid & 63, wave = tid >> 6;
  const int g = blockIdx.x, nbase = g*NPG;

  if (LOAD_M) {
    const float4* src = (const float4*)(min_or_h + (size_t)nbase*H);
    float4* dst = (float4*)mt;
    for (int i = tid; i < NPG*H/4; i += 1024) dst[i] = src[i];
  } else {
    for (int i = tid; i < H*H; i += 1024) {
      int k = i >> 6, f = i & 63;
      sWT[f*68 + k] = W[i];
    }
    __syncthreads();
    for (int gi = wave; gi < 50; gi += 16) {
      const float* hp = min_or_h + (size_t)(nbase + gi*8)*H;
      float acc[8] = {0,0,0,0,0,0,0,0};
      const float* wl = &sWT[lane*68];
      for (int kb = 0; kb < H; kb += 4) {
        float4 w4 = *(const float4*)(wl + kb);
        #pragma unroll
        for (int r = 0; r < 8; ++r) {
          float4 h4 = *(const float4*)(hp + r*H + kb);
          acc[r] += h4.x*w4.x + h4.y*w4.y + h4.z*w4.z + h4.w*w4.w;
        }
      }
      #pragma unroll
      for (int r = 0; r < 8; ++r)
        mt[(gi*8 + r)*H + lane] = acc[r];
    }
  }
  __syncthreads();

  const uint32_t grp = (uint32_t)(lane >> 4);
  const int fq = lane & 15;
  for (int v = wave; v < NPG; v += 16) {
    const uint32_t s = noff[nbase + v], e = noff[nbase + v + 1];
    float4 acc = make_float4(0.f, 0.f, 0.f, 0.f);
    uint32_t i = s;
    for (; i + 4 <= e; i += 4) {
      uint2 E0 = csr[i+0], E1 = csr[i+1], E2 = csr[i+2], E3 = csr[i+3];
      uint2 Eg = (grp == 0u) ? E0 : (grp == 1u) ? E1 : (grp == 2u) ? E2 : E3;
      float nm = __uint_as_float(Eg.y);
      float4 mv = *(const float4*)&mt[Eg.x*H + fq*4];
      acc.x += nm*mv.x; acc.y += nm*mv.y; acc.z += nm*mv.z; acc.w += nm*mv.w;
    }
    if (i + grp < e) {
      uint2 Eg = csr[i + grp];
      float nm = __uint_as_float(Eg.y);
      float4 mv = *(const float4*)&mt[Eg.x*H + fq*4];
      acc.x += nm*mv.x; acc.y += nm*mv.y; acc.z += nm*mv.z; acc.w += nm*mv.w;
    }
    #pragma unroll
    for (int d = 16; d <= 32; d <<= 1) {
      acc.x += __shfl_xor(acc.x, d);
      acc.y += __shfl_xor(acc.y, d);
      acc.z += __shfl_xor(acc.z, d);
      acc.w += __shfl_xor(acc.w, d);
    }
    if (lane < 16) {
      float4 b4 = *(const float4*)&bias[lane*4];
      float4 r;
      r.x = acc.x + b4.x; r.y = acc.y + b4.y;
      r.z = acc.z + b4.z; r.w = acc.w + b4.w;
      if (RELU) {
        r.x = fmaxf(r.x, 0.f); r.y = fmaxf(r.y, 0.f);
        r.z = fmaxf(r.z, 0.f); r.w = fmaxf(r.w, 0.f);
      }
      *(float4*)&hout[(size_t)(nbase + v)*H + lane*4] = r;
    }
  }
}

// ---------------- K5: readout partial  g += h3(64 graphs) x Wc(4 nodes) ----------
__global__ __launch_bounds__(1024) void k5_readout(
    const float* __restrict__ h3, const float* __restrict__ Wc,
    float* __restrict__ gbuf)
{
  extern __shared__ float smem[];
  float* swc = smem;            // 256*64
  float* sh  = smem + 256*64;   // 64 * 260 (pad 4)
  const int tid = threadIdx.x;
  const int vc = blockIdx.x % 100, gg = blockIdx.x / 100;
  const int v0 = vc*4, g0 = gg*64;

  const float4* wsrc = (const float4*)(Wc + (size_t)v0*64*64);
  float4* wdst = (float4*)swc;
  for (int i = tid; i < (256*64)/4; i += 1024) wdst[i] = wsrc[i];
  for (int i = tid; i < 64*256; i += 1024) {
    int j = i >> 8, rest = i & 255;
    int v = rest >> 6, k = rest & 63;
    sh[j*260 + rest] = h3[((size_t)(g0 + j)*NPG + v0 + v)*H + k];
  }
  __syncthreads();

  const int gr = tid >> 4, fq = tid & 15;
  float4 acc = make_float4(0.f, 0.f, 0.f, 0.f);
  const float* shp = &sh[gr*260];
  for (int t = 0; t < 256; ++t) {
    float hv = shp[t];
    float4 w4 = *(const float4*)&swc[t*64 + fq*4];
    acc.x += hv*w4.x; acc.y += hv*w4.y; acc.z += hv*w4.z; acc.w += hv*w4.w;
  }
  float* gp = gbuf + (size_t)(g0 + gr)*H + fq*4;
  atomicAdd(gp+0, acc.x); atomicAdd(gp+1, acc.y);
  atomicAdd(gp+2, acc.z); atomicAdd(gp+3, acc.w);
}

// ---------------- K6: out = (g + bc) @ Wl + bl ----------------
__global__ __launch_bounds__(512) void k6_final(
    const float* __restrict__ gbuf, const float* __restrict__ bc,
    const float* __restrict__ Wl, const float* __restrict__ bl,
    float* __restrict__ out)
{
  int t = threadIdx.x;           // 512 = 256 graphs * 2 outputs
  int gr = t >> 1, c = t & 1;
  float acc = bl[c];
  for (int f = 0; f < H; ++f)
    acc += (gbuf[gr*H + f] + bc[f]) * Wl[f*2 + c];
  out[gr*2 + c] = acc;
}

extern "C" void kernel_launch(void* const* d_in, const int* in_sizes, int n_in,
                              void* d_out, int out_size, void* d_ws, size_t ws_size,
                              hipStream_t stream)
{
  const float* x  = (const float*)d_in[0];
  const int*   ei = (const int*)d_in[1];
  const float* ew = (const float*)d_in[2];
  const float* W1 = (const float*)d_in[3];
  const float* b1 = (const float*)d_in[4];
  const float* W2 = (const float*)d_in[5];
  const float* b2 = (const float*)d_in[6];
  const float* W3 = (const float*)d_in[7];
  const float* b3 = (const float*)d_in[8];
  const float* Wc = (const float*)d_in[9];
  const float* bc = (const float*)d_in[10];
  const float* Wl = (const float*)d_in[11];
  const float* bl = (const float*)d_in[12];
  float* out = (float*)d_out;

  char* ws = (char*)d_ws;
  size_t o = 0;
  float*    A    = (float*)(ws + o);    o += (size_t)NN*H*4;        // 26.2 MB
  float*    B    = (float*)(ws + o);    o += (size_t)NN*H*4;        // 26.2 MB
  uint2*    csr  = (uint2*)(ws + o);    o += (size_t)G*CPG*8;       // 27.0 MB
  uint32_t* noff = (uint32_t*)(ws + o); o += ((size_t)NN + 4)*4;    // 0.4 MB
  float*    gbuf = (float*)(ws + o);    o += (size_t)G*H*4;         // 64 KB
  unsigned short* wfh = (unsigned short*)(ws + o); o += (size_t)13*4*64*8*2; // 53 KB
  unsigned short* wfl = (unsigned short*)(ws + o); o += (size_t)13*4*64*8*2; // 53 KB

  hipMemsetAsync(gbuf, 0, (size_t)G*H*4, stream);

  k0_build<<<G, 256, 0, stream>>>(ei, ew, csr, noff);
  kW_frag<<<104, 256, 0, stream>>>(W1, wfh, wfl);
  k1_mfma<<<NN/64, 256, 0, stream>>>(x, wfh, wfl, A);
  k_layer<1,1><<<G, 1024, NPG*H*4, stream>>>(A, nullptr, b1, csr, noff, B);
  k_layer<0,1><<<G, 1024, (NPG*H + 64*68)*4, stream>>>(B, W2, b2, csr, noff, A);
  k_layer<0,0><<<G, 1024, (NPG*H + 64*68)*4, stream>>>(A, W3, b3, csr, noff, B);
  k5_readout<<<400, 1024, (256*64 + 64*260)*4, stream>>>(B, Wc, gbuf);
  k6_final<<<1, 512, 0, stream>>>(gbuf, bc, Wl, bl, out);
}

// Round 3
// 430.401 us; speedup vs baseline: 2.1408x; 1.4720x over previous
//
#include <hip/hip_runtime.h>
#include <hip/hip_bf16.h>
#include <stdint.h>

#define G 256
#define NPG 400
#define DEG 32
#define FIN 400
#define H 64
#define NN (G*NPG)        // 102400
#define EE (G*NPG*DEG)    // 3276800
#define EPG (NPG*DEG)     // 12800 edges per graph
#define CPG (EPG+NPG)     // 13200 entries per graph (edges + self loops)
#define MTS 424           // MT lds stride (halves): 2-way banks, 16B aligned
#define ATS 420           // A-tile lds stride (floats): even-bank b128, 16B aligned

typedef __attribute__((ext_vector_type(8))) _Float16 h8;
typedef __attribute__((ext_vector_type(4))) float f32x4;

static __device__ __forceinline__ unsigned packh2(float a, float b) {
  unsigned short ua = __builtin_bit_cast(unsigned short, (_Float16)a);
  unsigned short ub = __builtin_bit_cast(unsigned short, (_Float16)b);
  return (unsigned)ua | ((unsigned)ub << 16);
}

static __device__ __forceinline__ h8 cvt8(float4 a, float4 b) {
  h8 r;
  r[0] = (_Float16)a.x; r[1] = (_Float16)a.y; r[2] = (_Float16)a.z; r[3] = (_Float16)a.w;
  r[4] = (_Float16)b.x; r[5] = (_Float16)b.y; r[6] = (_Float16)b.z; r[7] = (_Float16)b.w;
  return r;
}

// ---------------- kNorm: per-graph degree + packed normalized entries ----------
// entry.x = (dst_local<<16) | src_local ; entry.y = bits(norm fp32)
__global__ __launch_bounds__(256) void kNorm(
    const int* __restrict__ ei, const float* __restrict__ ew,
    uint2* __restrict__ ent)
{
  __shared__ float deg[NPG];
  __shared__ float dv[NPG];
  const int g = blockIdx.x, tid = threadIdx.x;
  const int ebase = g*EPG, nbase = g*NPG;
  const int* rowp = ei;          // sources
  const int* colp = ei + EE;     // targets
  for (int v = tid; v < NPG; v += 256) deg[v] = 1.0f;   // self-loop weight
  __syncthreads();
  for (int e = tid; e < EPG; e += 256)
    atomicAdd(&deg[colp[ebase+e] - nbase], ew[ebase+e]);
  __syncthreads();
  for (int v = tid; v < NPG; v += 256) dv[v] = rsqrtf(deg[v]);
  __syncthreads();
  uint2* eb = ent + (size_t)g*CPG;
  for (int e = tid; e < EPG; e += 256) {
    int src = rowp[ebase+e] - nbase;
    int dst = colp[ebase+e] - nbase;
    float nm = dv[src] * ew[ebase+e] * dv[dst];
    eb[e] = make_uint2(((unsigned)dst << 16) | (unsigned)src, __float_as_uint(nm));
  }
  for (int v = tid; v < NPG; v += 256)
    eb[EPG + v] = make_uint2(((unsigned)v << 16) | (unsigned)v, __float_as_uint(dv[v]*dv[v]));
}

// ---------------- kWc_pack: Wc -> fp16 B-fragment order [kt 800][nt 4][lane 64][j 8]
__global__ __launch_bounds__(256) void kWc_pack(
    const float* __restrict__ Wc, _Float16* __restrict__ wcf)
{
  int idx = blockIdx.x*256 + threadIdx.x;      // < 800*4*64*8 = 1638400
  int j = idx & 7, ln = (idx >> 3) & 63, nt = (idx >> 9) & 3, kt = idx >> 11;
  int k = kt*32 + (ln >> 4)*8 + j;             // 0..25599
  int col = nt*16 + (ln & 15);
  wcf[idx] = (_Float16)Wc[(size_t)k*64 + col];
}

// ---------------- kMega: all 3 GCN layers, one block per graph ----------------
// LDS: MT (M^T fp16 64x424) + union{ Wfrag fp16 | A-tile fp32 64x420 }
__global__ __launch_bounds__(512) void kMega(
    const float* __restrict__ x,
    const float* __restrict__ W1, const float* __restrict__ W2, const float* __restrict__ W3,
    const float* __restrict__ b1, const float* __restrict__ b2, const float* __restrict__ b3,
    const uint2* __restrict__ ent,
    _Float16* __restrict__ hA, _Float16* __restrict__ hB)
{
  extern __shared__ char smem[];
  _Float16* MT = (_Float16*)smem;                 // 64*424*2 = 54272 B
  char* U = smem + 64*MTS*2;
  float* sAT = (float*)U;                          // 64*420*4 = 107520 B
  _Float16* sWF = (_Float16*)U;                    // W frags (53248 B / 8192 B)

  const int tid = threadIdx.x, lane = tid & 63, wave = tid >> 6;
  const int g = blockIdx.x;
  const int l15 = lane & 15, kgrp = lane >> 4;
  const uint2* eb = ent + (size_t)g*CPG;

  // zero MT fully (incl. pad cols 400..423) once; pad stays zero across layers
  { float4* p = (float4*)MT;
    for (int i = tid; i < 64*MTS*2/16; i += 512) p[i] = make_float4(0,0,0,0); }

  for (int layer = 0; layer < 3; ++layer) {
    // ---- stage W fragments ----
    if (layer == 0) {
      for (int idx = tid; idx < 13*4*64*8; idx += 512) {
        int j = idx & 7, ln = (idx >> 3) & 63, nt = (idx >> 9) & 3, ks = idx >> 11;
        int k = ks*32 + (ln >> 4)*8 + j, col = nt*16 + (ln & 15);
        sWF[idx] = (k < FIN) ? (_Float16)W1[k*H + col] : (_Float16)0.f;
      }
    } else {
      const float* W = (layer == 1) ? W2 : W3;
      for (int idx = tid; idx < 2*4*64*8; idx += 512) {
        int j = idx & 7, ln = (idx >> 3) & 63, nt = (idx >> 9) & 3, ks = idx >> 11;
        sWF[idx] = (_Float16)W[(ks*32 + (ln >> 4)*8 + j)*H + nt*16 + (ln & 15)];
      }
    }
    __syncthreads();

    // ---- M-build: MT[feat][node] = (Hin @ W)^T ----
    const _Float16* hin = (layer == 1) ? hA : hB;   // used only for layer>0
    for (int rt = wave; rt < 25; rt += 8) {
      f32x4 acc[4] = {{0,0,0,0},{0,0,0,0},{0,0,0,0},{0,0,0,0}};
      h8 af[13];
      int nks;
      if (layer == 0) {
        nks = 13;
        const float* xp = x + ((size_t)g*NPG + rt*16 + l15)*FIN;
        #pragma unroll
        for (int ks = 0; ks < 13; ++ks) {
          int kb = ks*32 + kgrp*8;
          if (kb + 8 <= FIN) {
            float4 a0 = *(const float4*)(xp + kb);
            float4 a1 = *(const float4*)(xp + kb + 4);
            af[ks] = cvt8(a0, a1);
          } else {
            h8 z; for (int j = 0; j < 8; ++j) z[j] = (_Float16)0.f; af[ks] = z;
          }
        }
      } else {
        nks = 2;
        const _Float16* hp = hin + ((size_t)g*NPG + rt*16 + l15)*H;
        af[0] = *(const h8*)(hp + kgrp*8);
        af[1] = *(const h8*)(hp + 32 + kgrp*8);
      }
      for (int nt = 0; nt < 4; ++nt)
        for (int ks = 0; ks < nks; ++ks) {
          h8 bf = *(const h8*)&sWF[(((size_t)ks*4 + nt)*64 + lane)*8];
          acc[nt] = __builtin_amdgcn_mfma_f32_16x16x32_f16(af[ks], bf, acc[nt], 0, 0, 0);
        }
      // write transposed: node = rt*16 + kgrp*4 + r, feat = nt*16 + l15
      #pragma unroll
      for (int nt = 0; nt < 4; ++nt) {
        int feat = nt*16 + l15;
        #pragma unroll
        for (int rp = 0; rp < 2; ++rp) {
          int node = rt*16 + kgrp*4 + rp*2;
          *(unsigned*)&MT[feat*MTS + node] = packh2(acc[nt][rp*2], acc[nt][rp*2+1]);
        }
      }
    }
    __syncthreads();

    // ---- preload B-fragments (whole K) into registers, per-wave ----
    const int half = wave & 1, rsub = wave >> 1;
    const float* bptr = (layer == 0) ? b1 : (layer == 1) ? b2 : b3;
    float bv0 = bptr[half*32 + l15];
    float bv1 = bptr[half*32 + 16 + l15];
    h8 BF[13][2];
    #pragma unroll
    for (int ks = 0; ks < 13; ++ks)
      #pragma unroll
      for (int j2 = 0; j2 < 2; ++j2)
        BF[ks][j2] = *(const h8*)&MT[(half*32 + j2*16 + l15)*MTS + ks*32 + kgrp*8];

    _Float16* hout = (layer == 0) ? hA : (layer == 1) ? hB : hA;

    // ---- aggregation: 7 dst-tiles of 64 rows ----
    for (int t = 0; t < 7; ++t) {
      const int t0 = t*64;
      // zero A-tile
      { float4* p = (float4*)sAT;
        for (int i = tid; i < 64*ATS/4; i += 512) p[i] = make_float4(0,0,0,0); }
      __syncthreads();
      // scatter entries with dst in tile
      for (int e = tid; e < CPG; e += 512) {
        uint2 E = eb[e];
        int dst = (int)(E.x >> 16), src = (int)(E.x & 0xffffu);
        int r = dst - t0;
        if ((unsigned)r < 64u)
          atomicAdd(&sAT[r*ATS + src], __uint_as_float(E.y));
      }
      __syncthreads();
      // MFMA: out-tile = A-tile @ M
      const bool active = (t0 + rsub*16) < NPG;
      if (active) {
        f32x4 acc0 = {0,0,0,0}, acc1 = {0,0,0,0};
        const float* ap = &sAT[(rsub*16 + l15)*ATS];
        #pragma unroll
        for (int ks = 0; ks < 13; ++ks) {
          int kb = ks*32 + kgrp*8;
          float4 a0 = *(const float4*)(ap + kb);
          float4 a1 = *(const float4*)(ap + kb + 4);
          h8 af = cvt8(a0, a1);
          acc0 = __builtin_amdgcn_mfma_f32_16x16x32_f16(af, BF[ks][0], acc0, 0, 0, 0);
          acc1 = __builtin_amdgcn_mfma_f32_16x16x32_f16(af, BF[ks][1], acc1, 0, 0, 0);
        }
        #pragma unroll
        for (int r = 0; r < 4; ++r) {
          int node = t0 + rsub*16 + kgrp*4 + r;
          float v0 = acc0[r] + bv0, v1 = acc1[r] + bv1;
          if (layer < 2) { v0 = fmaxf(v0, 0.f); v1 = fmaxf(v1, 0.f); }
          _Float16* hp = hout + ((size_t)g*NPG + node)*H + half*32 + l15;
          hp[0]  = (_Float16)v0;
          hp[16] = (_Float16)v1;
        }
      }
      __syncthreads();
    }
    __threadfence_block();   // make h stores visible to next layer's reads
    __syncthreads();
  }
}

// ---------------- kRead: gbuf += h3[16 graphs] @ Wc (split-K, MFMA) ----------
__global__ __launch_bounds__(256) void kRead(
    const _Float16* __restrict__ h3, const _Float16* __restrict__ wcf,
    float* __restrict__ gbuf)
{
  const int tid = threadIdx.x, lane = tid & 63, nt = tid >> 6;
  const int l15 = lane & 15, kgrp = lane >> 4;
  const int rt = blockIdx.x & 15, kc = blockIdx.x >> 4;   // 16 row-tiles x 32 k-chunks
  f32x4 acc = {0,0,0,0};
  const _Float16* hp = h3 + (size_t)(rt*16 + l15)*25600;
  for (int ks = 0; ks < 25; ++ks) {
    int kt = kc*25 + ks;
    h8 af = *(const h8*)(hp + kt*32 + kgrp*8);
    h8 bf = *(const h8*)(wcf + (((size_t)kt*4 + nt)*64 + lane)*8);
    acc = __builtin_amdgcn_mfma_f32_16x16x32_f16(af, bf, acc, 0, 0, 0);
  }
  #pragma unroll
  for (int r = 0; r < 4; ++r)
    atomicAdd(&gbuf[(size_t)(rt*16 + kgrp*4 + r)*H + nt*16 + l15], acc[r]);
}

// ---------------- k6: out = (g + bc) @ Wl + bl ----------------
__global__ __launch_bounds__(512) void k6_final(
    const float* __restrict__ gbuf, const float* __restrict__ bc,
    const float* __restrict__ Wl, const float* __restrict__ bl,
    float* __restrict__ out)
{
  int t = threadIdx.x;           // 512 = 256 graphs * 2 outputs
  int gr = t >> 1, c = t & 1;
  float acc = bl[c];
  for (int f = 0; f < H; ++f)
    acc += (gbuf[gr*H + f] + bc[f]) * Wl[f*2 + c];
  out[gr*2 + c] = acc;
}

extern "C" void kernel_launch(void* const* d_in, const int* in_sizes, int n_in,
                              void* d_out, int out_size, void* d_ws, size_t ws_size,
                              hipStream_t stream)
{
  const float* x  = (const float*)d_in[0];
  const int*   ei = (const int*)d_in[1];
  const float* ew = (const float*)d_in[2];
  const float* W1 = (const float*)d_in[3];
  const float* b1 = (const float*)d_in[4];
  const float* W2 = (const float*)d_in[5];
  const float* b2 = (const float*)d_in[6];
  const float* W3 = (const float*)d_in[7];
  const float* b3 = (const float*)d_in[8];
  const float* Wc = (const float*)d_in[9];
  const float* bc = (const float*)d_in[10];
  const float* Wl = (const float*)d_in[11];
  const float* bl = (const float*)d_in[12];
  float* out = (float*)d_out;

  char* ws = (char*)d_ws;
  size_t o = 0;
  uint2*     ent  = (uint2*)(ws + o);     o += (size_t)G*CPG*8;      // 27.0 MB
  _Float16*  hA   = (_Float16*)(ws + o);  o += (size_t)NN*H*2;       // 13.1 MB
  _Float16*  hB   = (_Float16*)(ws + o);  o += (size_t)NN*H*2;       // 13.1 MB
  _Float16*  wcf  = (_Float16*)(ws + o);  o += (size_t)800*4*64*8*2; // 3.3 MB
  float*     gbuf = (float*)(ws + o);     o += (size_t)G*H*4;        // 64 KB

  hipMemsetAsync(gbuf, 0, (size_t)G*H*4, stream);

  kWc_pack<<<6400, 256, 0, stream>>>(Wc, wcf);
  kNorm<<<G, 256, 0, stream>>>(ei, ew, ent);
  const int megaLds = 64*MTS*2 + 64*ATS*4;   // 54272 + 107520 = 161792 B
  kMega<<<G, 512, megaLds, stream>>>(x, W1, W2, W3, b1, b2, b3, ent, hA, hB);
  kRead<<<512, 256, 0, stream>>>(hA, wcf, gbuf);
  k6_final<<<1, 512, 0, stream>>>(gbuf, bc, Wl, bl, out);
}

// Round 4
// 368.079 us; speedup vs baseline: 2.5032x; 1.1693x over previous
//
#include <hip/hip_runtime.h>
#include <hip/hip_bf16.h>
#include <stdint.h>

#define G 256
#define NPG 400
#define DEG 32
#define FIN 400
#define H 64
#define NN (G*NPG)        // 102400
#define EE (G*NPG*DEG)    // 3276800
#define EPG (NPG*DEG)     // 12800 edges per graph
#define CPG (EPG+NPG)     // 13200 entries per graph (edges + self loops)
#define MTS 424           // MT lds stride (halves)
#define ATS 420           // A-tile lds stride (floats)

typedef __attribute__((ext_vector_type(8))) _Float16 h8;
typedef __attribute__((ext_vector_type(4))) float f32x4;

static __device__ __forceinline__ unsigned packh2(float a, float b) {
  unsigned short ua = __builtin_bit_cast(unsigned short, (_Float16)a);
  unsigned short ub = __builtin_bit_cast(unsigned short, (_Float16)b);
  return (unsigned)ua | ((unsigned)ub << 16);
}

static __device__ __forceinline__ h8 cvt8(float4 a, float4 b) {
  h8 r;
  r[0] = (_Float16)a.x; r[1] = (_Float16)a.y; r[2] = (_Float16)a.z; r[3] = (_Float16)a.w;
  r[4] = (_Float16)b.x; r[5] = (_Float16)b.y; r[6] = (_Float16)b.z; r[7] = (_Float16)b.w;
  return r;
}

// ---------------- kNorm: degree + normalized entries, bucketed by dst tile ----
// entry.x = (dst_local<<16) | src_local ; entry.y = bits(norm fp32)
__global__ __launch_bounds__(256) void kNorm(
    const int* __restrict__ ei, const float* __restrict__ ew,
    uint2* __restrict__ ent, uint32_t* __restrict__ boff)
{
  __shared__ float deg[NPG];
  __shared__ float dv[NPG];
  __shared__ uint32_t bcnt[8], bpos[8];
  const int g = blockIdx.x, tid = threadIdx.x;
  const int ebase = g*EPG, nbase = g*NPG;
  const int* rowp = ei;          // sources
  const int* colp = ei + EE;     // targets
  if (tid < 8) bcnt[tid] = 0u;
  for (int v = tid; v < NPG; v += 256) deg[v] = 1.0f;   // self-loop weight
  __syncthreads();
  for (int e = tid; e < EPG; e += 256) {
    int c = colp[ebase+e] - nbase;
    atomicAdd(&deg[c], ew[ebase+e]);
    atomicAdd(&bcnt[c >> 6], 1u);
  }
  __syncthreads();
  for (int v = tid; v < NPG; v += 256) dv[v] = rsqrtf(deg[v]);
  if (tid == 0) {
    uint32_t s = 0;
    #pragma unroll
    for (int t = 0; t < 7; ++t) {
      uint32_t c = bcnt[t] + ((t < 6) ? 64u : 16u);   // + self loops in tile
      bcnt[t] = s;        // bucket start
      bpos[t] = s;        // working cursor
      s += c;
    }
  }
  __syncthreads();
  if (tid < 7) boff[g*8 + tid] = bcnt[tid];
  if (tid == 7) boff[g*8 + 7] = (uint32_t)CPG;
  uint2* eb = ent + (size_t)g*CPG;
  for (int e = tid; e < EPG; e += 256) {
    int src = rowp[ebase+e] - nbase;
    int dst = colp[ebase+e] - nbase;
    float nm = dv[src] * ew[ebase+e] * dv[dst];
    uint32_t p = atomicAdd(&bpos[dst >> 6], 1u);
    eb[p] = make_uint2(((unsigned)dst << 16) | (unsigned)src, __float_as_uint(nm));
  }
  for (int v = tid; v < NPG; v += 256) {
    uint32_t p = atomicAdd(&bpos[v >> 6], 1u);
    eb[p] = make_uint2(((unsigned)v << 16) | (unsigned)v, __float_as_uint(dv[v]*dv[v]));
  }
}

// ---------------- kWc_pack: Wc -> fp16 B-fragment order [kt 800][nt 4][lane 64][j 8]
__global__ __launch_bounds__(256) void kWc_pack(
    const float* __restrict__ Wc, _Float16* __restrict__ wcf)
{
  int idx = blockIdx.x*256 + threadIdx.x;      // < 800*4*64*8 = 1638400
  int j = idx & 7, ln = (idx >> 3) & 63, nt = (idx >> 9) & 3, kt = idx >> 11;
  int k = kt*32 + (ln >> 4)*8 + j;             // 0..25599
  int col = nt*16 + (ln & 15);
  wcf[idx] = (_Float16)Wc[(size_t)k*64 + col];
}

// ---------------- kMega: all 3 GCN layers, one block per graph, 16 waves -----
__global__ __launch_bounds__(1024) void kMega(
    const float* __restrict__ x,
    const float* __restrict__ W1, const float* __restrict__ W2, const float* __restrict__ W3,
    const float* __restrict__ b1, const float* __restrict__ b2, const float* __restrict__ b3,
    const uint2* __restrict__ ent, const uint32_t* __restrict__ boff,
    _Float16* __restrict__ hA, _Float16* __restrict__ hB)
{
  extern __shared__ char smem[];
  _Float16* MT = (_Float16*)smem;                 // 64*424*2 = 54272 B
  char* U = smem + 64*MTS*2;
  float* sAT = (float*)U;                          // 64*420*4 = 107520 B
  _Float16* sWF = (_Float16*)U;                    // W frags (53248 B / 8192 B)

  const int tid = threadIdx.x, lane = tid & 63, wave = tid >> 6;
  const int g = blockIdx.x;
  const int l15 = lane & 15, kgrp = lane >> 4;
  const uint2* eb = ent + (size_t)g*CPG;
  const uint32_t* bo = boff + g*8;

  // zero MT fully (incl. pad cols) once; pad stays zero across layers
  { float4* p = (float4*)MT;
    for (int i = tid; i < 64*MTS*2/16; i += 1024) p[i] = make_float4(0,0,0,0); }

  for (int layer = 0; layer < 3; ++layer) {
    // ---- stage W fragments (into U region; A-tile dead here) ----
    if (layer == 0) {
      for (int idx = tid; idx < 13*4*64*8; idx += 1024) {
        int j = idx & 7, ln = (idx >> 3) & 63, nt = (idx >> 9) & 3, ks = idx >> 11;
        int k = ks*32 + (ln >> 4)*8 + j, col = nt*16 + (ln & 15);
        sWF[idx] = (k < FIN) ? (_Float16)W1[k*H + col] : (_Float16)0.f;
      }
    } else {
      const float* W = (layer == 1) ? W2 : W3;
      for (int idx = tid; idx < 2*4*64*8; idx += 1024) {
        int j = idx & 7, ln = (idx >> 3) & 63, nt = (idx >> 9) & 3, ks = idx >> 11;
        sWF[idx] = (_Float16)W[(ks*32 + (ln >> 4)*8 + j)*H + nt*16 + (ln & 15)];
      }
    }
    __syncthreads();

    // ---- M-build: MT[feat][node] = (Hin @ W)^T ----
    const _Float16* hin = (layer == 1) ? hA : hB;   // used only for layer>0
    for (int rt = wave; rt < 25; rt += 16) {
      f32x4 acc[4] = {{0,0,0,0},{0,0,0,0},{0,0,0,0},{0,0,0,0}};
      h8 af[13];
      int nks;
      if (layer == 0) {
        nks = 13;
        const float* xp = x + ((size_t)g*NPG + rt*16 + l15)*FIN;
        #pragma unroll
        for (int ks = 0; ks < 13; ++ks) {
          int kb = ks*32 + kgrp*8;
          if (kb + 8 <= FIN) {
            float4 a0 = *(const float4*)(xp + kb);
            float4 a1 = *(const float4*)(xp + kb + 4);
            af[ks] = cvt8(a0, a1);
          } else {
            h8 z; for (int j = 0; j < 8; ++j) z[j] = (_Float16)0.f; af[ks] = z;
          }
        }
      } else {
        nks = 2;
        const _Float16* hp = hin + ((size_t)g*NPG + rt*16 + l15)*H;
        af[0] = *(const h8*)(hp + kgrp*8);
        af[1] = *(const h8*)(hp + 32 + kgrp*8);
      }
      for (int nt = 0; nt < 4; ++nt)
        for (int ks = 0; ks < nks; ++ks) {
          h8 bf = *(const h8*)&sWF[(((size_t)ks*4 + nt)*64 + lane)*8];
          acc[nt] = __builtin_amdgcn_mfma_f32_16x16x32_f16(af[ks], bf, acc[nt], 0, 0, 0);
        }
      #pragma unroll
      for (int nt = 0; nt < 4; ++nt) {
        int feat = nt*16 + l15;
        #pragma unroll
        for (int rp = 0; rp < 2; ++rp) {
          int node = rt*16 + kgrp*4 + rp*2;
          *(unsigned*)&MT[feat*MTS + node] = packh2(acc[nt][rp*2], acc[nt][rp*2+1]);
        }
      }
    }
    __syncthreads();

    // ---- per-wave roles + B-fragment preload (whole K) ----
    const int rsub = wave & 3, ntw = wave >> 2;
    const float* bptr = (layer == 0) ? b1 : (layer == 1) ? b2 : b3;
    const float bv = bptr[ntw*16 + l15];
    h8 BF[13];
    #pragma unroll
    for (int ks = 0; ks < 13; ++ks)
      BF[ks] = *(const h8*)&MT[(ntw*16 + l15)*MTS + ks*32 + kgrp*8];

    _Float16* hout = (layer == 0) ? hA : (layer == 1) ? hB : hA;

    // ---- aggregation: 7 dst-tiles of 64 rows ----
    for (int t = 0; t < 7; ++t) {
      const int t0 = t*64;
      const uint32_t s0 = bo[t], s1 = bo[t+1];
      // prefetch this tile's entries into regs (overlaps with zeroing)
      const uint32_t e0 = s0 + tid;
      uint2 E0 = make_uint2(0,0), E1 = make_uint2(0,0);
      uint2 E2 = make_uint2(0,0), E3 = make_uint2(0,0);
      if (e0        < s1) E0 = eb[e0];
      if (e0 + 1024 < s1) E1 = eb[e0 + 1024];
      if (e0 + 2048 < s1) E2 = eb[e0 + 2048];
      if (e0 + 3072 < s1) E3 = eb[e0 + 3072];
      // zero A-tile
      { float4* p = (float4*)sAT;
        for (int i = tid; i < 64*ATS/4; i += 1024) p[i] = make_float4(0,0,0,0); }
      __syncthreads();
      // scatter
      if (e0        < s1) atomicAdd(&sAT[((int)(E0.x >> 16) - t0)*ATS + (int)(E0.x & 0xffffu)], __uint_as_float(E0.y));
      if (e0 + 1024 < s1) atomicAdd(&sAT[((int)(E1.x >> 16) - t0)*ATS + (int)(E1.x & 0xffffu)], __uint_as_float(E1.y));
      if (e0 + 2048 < s1) atomicAdd(&sAT[((int)(E2.x >> 16) - t0)*ATS + (int)(E2.x & 0xffffu)], __uint_as_float(E2.y));
      if (e0 + 3072 < s1) atomicAdd(&sAT[((int)(E3.x >> 16) - t0)*ATS + (int)(E3.x & 0xffffu)], __uint_as_float(E3.y));
      for (uint32_t e = e0 + 4096; e < s1; e += 1024) {     // overflow guard
        uint2 E = eb[e];
        atomicAdd(&sAT[((int)(E.x >> 16) - t0)*ATS + (int)(E.x & 0xffffu)], __uint_as_float(E.y));
      }
      __syncthreads();
      // MFMA: out-tile rows = A-tile @ M
      if (t0 + rsub*16 < NPG) {
        f32x4 acc = {0,0,0,0};
        const float* ap = &sAT[(rsub*16 + l15)*ATS];
        #pragma unroll
        for (int ks = 0; ks < 13; ++ks) {
          int kb = ks*32 + kgrp*8;
          float4 a0 = *(const float4*)(ap + kb);
          float4 a1 = *(const float4*)(ap + kb + 4);
          h8 af = cvt8(a0, a1);
          acc = __builtin_amdgcn_mfma_f32_16x16x32_f16(af, BF[ks], acc, 0, 0, 0);
        }
        #pragma unroll
        for (int r = 0; r < 4; ++r) {
          int node = t0 + rsub*16 + kgrp*4 + r;
          float v = acc[r] + bv;
          if (layer < 2) v = fmaxf(v, 0.f);
          hout[((size_t)g*NPG + node)*H + ntw*16 + l15] = (_Float16)v;
        }
      }
      __syncthreads();
    }
    __threadfence_block();
    __syncthreads();
  }
}

// ---------------- kRead: gbuf += h3[16 graphs] @ Wc (split-K, MFMA) ----------
__global__ __launch_bounds__(256) void kRead(
    const _Float16* __restrict__ h3, const _Float16* __restrict__ wcf,
    float* __restrict__ gbuf)
{
  const int tid = threadIdx.x, lane = tid & 63, nt = tid >> 6;
  const int l15 = lane & 15, kgrp = lane >> 4;
  const int rt = blockIdx.x & 15, kc = blockIdx.x >> 4;   // 16 row-tiles x 32 k-chunks
  f32x4 acc = {0,0,0,0};
  const _Float16* hp = h3 + (size_t)(rt*16 + l15)*25600;
  for (int ks = 0; ks < 25; ++ks) {
    int kt = kc*25 + ks;
    h8 af = *(const h8*)(hp + kt*32 + kgrp*8);
    h8 bf = *(const h8*)(wcf + (((size_t)kt*4 + nt)*64 + lane)*8);
    acc = __builtin_amdgcn_mfma_f32_16x16x32_f16(af, bf, acc, 0, 0, 0);
  }
  #pragma unroll
  for (int r = 0; r < 4; ++r)
    atomicAdd(&gbuf[(size_t)(rt*16 + kgrp*4 + r)*H + nt*16 + l15], acc[r]);
}

// ---------------- k6: out = (g + bc) @ Wl + bl ----------------
__global__ __launch_bounds__(512) void k6_final(
    const float* __restrict__ gbuf, const float* __restrict__ bc,
    const float* __restrict__ Wl, const float* __restrict__ bl,
    float* __restrict__ out)
{
  int t = threadIdx.x;           // 512 = 256 graphs * 2 outputs
  int gr = t >> 1, c = t & 1;
  float acc = bl[c];
  for (int f = 0; f < H; ++f)
    acc += (gbuf[gr*H + f] + bc[f]) * Wl[f*2 + c];
  out[gr*2 + c] = acc;
}

extern "C" void kernel_launch(void* const* d_in, const int* in_sizes, int n_in,
                              void* d_out, int out_size, void* d_ws, size_t ws_size,
                              hipStream_t stream)
{
  const float* x  = (const float*)d_in[0];
  const int*   ei = (const int*)d_in[1];
  const float* ew = (const float*)d_in[2];
  const float* W1 = (const float*)d_in[3];
  const float* b1 = (const float*)d_in[4];
  const float* W2 = (const float*)d_in[5];
  const float* b2 = (const float*)d_in[6];
  const float* W3 = (const float*)d_in[7];
  const float* b3 = (const float*)d_in[8];
  const float* Wc = (const float*)d_in[9];
  const float* bc = (const float*)d_in[10];
  const float* Wl = (const float*)d_in[11];
  const float* bl = (const float*)d_in[12];
  float* out = (float*)d_out;

  char* ws = (char*)d_ws;
  size_t o = 0;
  uint2*     ent  = (uint2*)(ws + o);     o += (size_t)G*CPG*8;      // 27.0 MB
  uint32_t*  boff = (uint32_t*)(ws + o);  o += (size_t)G*8*4;        // 8 KB
  _Float16*  hA   = (_Float16*)(ws + o);  o += (size_t)NN*H*2;       // 13.1 MB
  _Float16*  hB   = (_Float16*)(ws + o);  o += (size_t)NN*H*2;       // 13.1 MB
  _Float16*  wcf  = (_Float16*)(ws + o);  o += (size_t)800*4*64*8*2; // 3.3 MB
  float*     gbuf = (float*)(ws + o);     o += (size_t)G*H*4;        // 64 KB

  hipMemsetAsync(gbuf, 0, (size_t)G*H*4, stream);

  kWc_pack<<<6400, 256, 0, stream>>>(Wc, wcf);
  kNorm<<<G, 256, 0, stream>>>(ei, ew, ent, boff);
  const int megaLds = 64*MTS*2 + 64*ATS*4;   // 54272 + 107520 = 161792 B
  kMega<<<G, 1024, megaLds, stream>>>(x, W1, W2, W3, b1, b2, b3, ent, boff, hA, hB);
  kRead<<<512, 256, 0, stream>>>(hA, wcf, gbuf);
  k6_final<<<1, 512, 0, stream>>>(gbuf, bc, Wl, bl, out);
}

// Round 7
// 297.691 us; speedup vs baseline: 3.0951x; 1.2364x over previous
//
#include <hip/hip_runtime.h>
#include <hip/hip_bf16.h>
#include <stdint.h>

#define G 256
#define NPG 400
#define DEG 32
#define FIN 400
#define H 64
#define NN (G*NPG)        // 102400
#define EE (G*NPG*DEG)    // 3276800
#define EPG (NPG*DEG)     // 12800 edges per graph
#define CPG (EPG+NPG)     // 13200 entries per graph (edges + self loops)
#define NTILE 13          // 32-row dst tiles per graph (12x32 + 16)
#define ATS 420           // A-tile LDS stride (floats)
#define HTS 72            // h-tile LDS stride (halves)
#define MTSZ 25600        // per-graph M^T elems (64*400)

// wf buffer layout (halves)
#define W1F_OFF 0
#define W1F_N   (13*4*64*8)          // 26624
#define W2F_OFF (W1F_OFF + W1F_N)    // 26624
#define W2F_N   (2*4*64*8)           // 4096
#define W3F_OFF (W2F_OFF + W2F_N)    // 30720
#define WCF_OFF (W3F_OFF + W2F_N)    // 34816
#define WCF_N   (800*4*64*8)         // 1638400
#define WF_TOT  (WCF_OFF + WCF_N)    // 1673216

typedef __attribute__((ext_vector_type(8))) _Float16 h8;
typedef __attribute__((ext_vector_type(4))) float f32x4;

static __device__ __forceinline__ unsigned packh2(float a, float b) {
  unsigned short ua = __builtin_bit_cast(unsigned short, (_Float16)a);
  unsigned short ub = __builtin_bit_cast(unsigned short, (_Float16)b);
  return (unsigned)ua | ((unsigned)ub << 16);
}

static __device__ __forceinline__ h8 cvt8(float4 a, float4 b) {
  h8 r;
  r[0] = (_Float16)a.x; r[1] = (_Float16)a.y; r[2] = (_Float16)a.z; r[3] = (_Float16)a.w;
  r[4] = (_Float16)b.x; r[5] = (_Float16)b.y; r[6] = (_Float16)b.z; r[7] = (_Float16)b.w;
  return r;
}

// ---------------- kNorm: degree + normalized entries bucketed by 32-row tile --
// entry.x = (dst_local<<16) | src_local ; entry.y = bits(norm fp32)
__global__ __launch_bounds__(256) void kNorm(
    const int* __restrict__ ei, const float* __restrict__ ew,
    uint2* __restrict__ ent, uint32_t* __restrict__ boff)
{
  __shared__ float deg[NPG];
  __shared__ float dv[NPG];
  __shared__ uint32_t bcnt[NTILE], bpos[NTILE];
  const int g = blockIdx.x, tid = threadIdx.x;
  const int ebase = g*EPG, nbase = g*NPG;
  const int* rowp = ei;          // sources
  const int* colp = ei + EE;     // targets
  if (tid < NTILE) bcnt[tid] = 0u;
  for (int v = tid; v < NPG; v += 256) deg[v] = 1.0f;   // self-loop weight
  __syncthreads();
  for (int e = tid; e < EPG; e += 256) {
    int c = colp[ebase+e] - nbase;
    atomicAdd(&deg[c], ew[ebase+e]);
    atomicAdd(&bcnt[c >> 5], 1u);
  }
  __syncthreads();
  for (int v = tid; v < NPG; v += 256) dv[v] = rsqrtf(deg[v]);
  if (tid == 0) {
    uint32_t s = 0;
    #pragma unroll
    for (int t = 0; t < NTILE; ++t) {
      uint32_t c = bcnt[t] + ((t < 12) ? 32u : 16u);   // + self loops in tile
      bcnt[t] = s; bpos[t] = s; s += c;
    }
  }
  __syncthreads();
  if (tid < NTILE) boff[g*16 + tid] = bcnt[tid];
  if (tid == NTILE) boff[g*16 + NTILE] = (uint32_t)CPG;
  uint2* eb = ent + (size_t)g*CPG;
  for (int e = tid; e < EPG; e += 256) {
    int src = rowp[ebase+e] - nbase;
    int dst = colp[ebase+e] - nbase;
    float nm = dv[src] * ew[ebase+e] * dv[dst];
    uint32_t p = atomicAdd(&bpos[dst >> 5], 1u);
    eb[p] = make_uint2(((unsigned)dst << 16) | (unsigned)src, __float_as_uint(nm));
  }
  for (int v = tid; v < NPG; v += 256) {
    uint32_t p = atomicAdd(&bpos[v >> 5], 1u);
    eb[p] = make_uint2(((unsigned)v << 16) | (unsigned)v, __float_as_uint(dv[v]*dv[v]));
  }
}

// ---------------- kPack: all weights -> fp16 MFMA B-fragment order ----------
__global__ __launch_bounds__(256) void kPack(
    const float* __restrict__ W1, const float* __restrict__ W2,
    const float* __restrict__ W3, const float* __restrict__ Wc,
    _Float16* __restrict__ wf)
{
  int idx = blockIdx.x*256 + threadIdx.x;
  if (idx >= WF_TOT) return;
  if (idx < W2F_OFF) {                       // W1: [ks 13][nt 4][lane][j]
    int i = idx;
    int j = i & 7, ln = (i >> 3) & 63, nt = (i >> 9) & 3, ks = i >> 11;
    int k = ks*32 + (ln >> 4)*8 + j, col = nt*16 + (ln & 15);
    wf[idx] = (k < FIN) ? (_Float16)W1[k*H + col] : (_Float16)0.f;
  } else if (idx < W3F_OFF) {                // W2: [ks 2][nt 4][lane][j]
    int i = idx - W2F_OFF;
    int j = i & 7, ln = (i >> 3) & 63, nt = (i >> 9) & 3, ks = i >> 11;
    wf[idx] = (_Float16)W2[(ks*32 + (ln >> 4)*8 + j)*H + nt*16 + (ln & 15)];
  } else if (idx < WCF_OFF) {                // W3
    int i = idx - W3F_OFF;
    int j = i & 7, ln = (i >> 3) & 63, nt = (i >> 9) & 3, ks = i >> 11;
    wf[idx] = (_Float16)W3[(ks*32 + (ln >> 4)*8 + j)*H + nt*16 + (ln & 15)];
  } else {                                   // Wc with k' = feat*400 + node perm
    int i = idx - WCF_OFF;
    int j = i & 7, ln = (i >> 3) & 63, nt = (i >> 9) & 3, kt = i >> 11;
    int kp = kt*32 + (ln >> 4)*8 + j;        // 0..25599
    int node = kp % 400, feat = kp / 400;
    int col = nt*16 + (ln & 15);
    wf[idx] = (_Float16)Wc[((size_t)node*64 + feat)*64 + col];
  }
}

// ---------------- kM1: MT1 = (x @ W1)^T  per-graph [feat][node], fp16 -------
__global__ __launch_bounds__(256, 4) void kM1(
    const float* __restrict__ x, const _Float16* __restrict__ wf,
    _Float16* __restrict__ mt1)
{
  __shared__ _Float16 sh[64*HTS];            // 9216 B out-stage
  const int tid = threadIdx.x, lane = tid & 63, wave = tid >> 6;
  const int l15 = lane & 15, kgrp = lane >> 4;
  const int g = blockIdx.y, b = blockIdx.x;  // b < 7, nodes b*64..b*64+63
  const int node_l = b*64 + wave*16 + l15;
  const int arow = (node_l < NPG) ? node_l : NPG-1;
  const float* xp = x + ((size_t)g*NPG + arow)*FIN;

  h8 af[13];
  #pragma unroll
  for (int ks = 0; ks < 13; ++ks) {
    int kb = ks*32 + kgrp*8;
    if (kb + 8 <= FIN) {
      float4 a0 = *(const float4*)(xp + kb);
      float4 a1 = *(const float4*)(xp + kb + 4);
      af[ks] = cvt8(a0, a1);
    } else {
      h8 z;
      #pragma unroll
      for (int j = 0; j < 8; ++j) z[j] = (_Float16)0.f;
      af[ks] = z;
    }
  }
  f32x4 acc[4] = {{0,0,0,0},{0,0,0,0},{0,0,0,0},{0,0,0,0}};
  for (int nt = 0; nt < 4; ++nt)
    for (int ks = 0; ks < 13; ++ks) {
      h8 bf = *(const h8*)&wf[W1F_OFF + (((size_t)ks*4 + nt)*64 + lane)*8];
      acc[nt] = __builtin_amdgcn_mfma_f32_16x16x32_f16(af[ks], bf, acc[nt], 0, 0, 0);
    }
  // stage [node_local][feat]
  #pragma unroll
  for (int nt = 0; nt < 4; ++nt) {
    int feat = nt*16 + l15;
    #pragma unroll
    for (int r = 0; r < 4; ++r)
      sh[(wave*16 + kgrp*4 + r)*HTS + feat] = (_Float16)acc[nt][r];
  }
  __syncthreads();
  // transposed coalesced store: MT1[g][feat][b*64 + 0..63]
  const unsigned short* shu = (const unsigned short*)sh;
  for (int i = tid; i < 64*16; i += 256) {
    int feat = i >> 4, seg = i & 15;
    int nl = seg*4, gn = b*64 + nl;
    if (gn < NPG) {
      uint2 u;
      u.x = (unsigned)shu[(nl+0)*HTS + feat] | ((unsigned)shu[(nl+1)*HTS + feat] << 16);
      u.y = (unsigned)shu[(nl+2)*HTS + feat] | ((unsigned)shu[(nl+3)*HTS + feat] << 16);
      *(uint2*)&mt1[(size_t)g*MTSZ + feat*400 + gn] = u;
    }
  }
}

// ---------------- kAgg<WMUL>: one 32-row dst tile: scatter + agg MFMA --------
// WMUL=1: + bias + relu + fused next-layer GEMM -> MT_out.  WMUL=0: + bias -> MT-layout out.
template<int WMUL>
__global__ __launch_bounds__(512, 4) void kAgg(
    const _Float16* __restrict__ mtin, const _Float16* __restrict__ wfn,
    const float* __restrict__ bias,
    const uint2* __restrict__ ent, const uint32_t* __restrict__ boff,
    _Float16* __restrict__ out)
{
  extern __shared__ char smem[];
  float* sAT = (float*)smem;                     // 32*420*4 = 53760 B
  _Float16* sh = (_Float16*)(smem + 32*ATS*4);   // 32*72*2  = 4608 B
  const int tid = threadIdx.x, lane = tid & 63, wave = tid >> 6;
  const int l15 = lane & 15, kgrp = lane >> 4;
  const int bid = blockIdx.x;
  const int g = bid & 255, t = bid >> 8;         // same-graph blocks share XCD
  const int t0 = t*32;
  const int rsub = wave & 1, nt = wave >> 1;
  const uint2* eb = ent + (size_t)g*CPG;
  const uint32_t s0 = boff[g*16 + t], s1 = boff[g*16 + t + 1];

  // global prefetches (all independent; overlap with zeroing)
  h8 BF[13];
  const _Float16* mrow = mtin + (size_t)g*MTSZ + (nt*16 + l15)*400;
  #pragma unroll
  for (int ks = 0; ks < 13; ++ks)
    BF[ks] = *(const h8*)(mrow + ks*32 + kgrp*8);
  const float bv = bias[nt*16 + l15];
  h8 WF2[2];
  if (WMUL) {
    WF2[0] = *(const h8*)&wfn[((size_t)(0*4 + nt)*64 + lane)*8];
    WF2[1] = *(const h8*)&wfn[((size_t)(1*4 + nt)*64 + lane)*8];
  }
  const uint32_t e0 = s0 + tid;
  uint2 E0 = make_uint2(0,0), E1 = make_uint2(0,0), E2 = make_uint2(0,0);
  if (e0        < s1) E0 = eb[e0];
  if (e0 + 512  < s1) E1 = eb[e0 + 512];
  if (e0 + 1024 < s1) E2 = eb[e0 + 1024];

  // zero A-tile
  { float4* p = (float4*)sAT;
    for (int i = tid; i < 32*ATS/4; i += 512) p[i] = make_float4(0,0,0,0); }
  __syncthreads();

  // scatter
  if (e0        < s1) atomicAdd(&sAT[((int)(E0.x >> 16) - t0)*ATS + (int)(E0.x & 0xffffu)], __uint_as_float(E0.y));
  if (e0 + 512  < s1) atomicAdd(&sAT[((int)(E1.x >> 16) - t0)*ATS + (int)(E1.x & 0xffffu)], __uint_as_float(E1.y));
  if (e0 + 1024 < s1) atomicAdd(&sAT[((int)(E2.x >> 16) - t0)*ATS + (int)(E2.x & 0xffffu)], __uint_as_float(E2.y));
  for (uint32_t e = e0 + 1536; e < s1; e += 512) {
    uint2 E = eb[e];
    atomicAdd(&sAT[((int)(E.x >> 16) - t0)*ATS + (int)(E.x & 0xffffu)], __uint_as_float(E.y));
  }
  __syncthreads();

  // agg MFMA: rows rsub*16.., cols nt*16..
  f32x4 acc = {0,0,0,0};
  const float* ap = &sAT[(rsub*16 + l15)*ATS];
  #pragma unroll
  for (int ks = 0; ks < 13; ++ks) {
    int kb = ks*32 + kgrp*8;
    float4 a0 = *(const float4*)(ap + kb);
    float4 a1 = *(const float4*)(ap + kb + 4);
    acc = __builtin_amdgcn_mfma_f32_16x16x32_f16(cvt8(a0, a1), BF[ks], acc, 0, 0, 0);
  }

  if (!WMUL) {
    // layer 3: bias only, store MT layout (= h3 transposed k' order)
    int node0 = t0 + rsub*16 + kgrp*4;
    if (node0 < NPG) {
      uint2 u;
      u.x = packh2(acc[0] + bv, acc[1] + bv);
      u.y = packh2(acc[2] + bv, acc[3] + bv);
      *(uint2*)&out[(size_t)g*MTSZ + (nt*16 + l15)*400 + node0] = u;
    }
  } else {
    // bias + relu -> h-tile LDS
    int nl0 = rsub*16 + kgrp*4;
    #pragma unroll
    for (int r = 0; r < 4; ++r)
      sh[(nl0 + r)*HTS + nt*16 + l15] = (_Float16)fmaxf(acc[r] + bv, 0.f);
    __syncthreads();
    // fused next-layer GEMM: M_out-tile = h_tile @ Wn
    f32x4 acc2 = {0,0,0,0};
    const _Float16* hp = &sh[(rsub*16 + l15)*HTS];
    acc2 = __builtin_amdgcn_mfma_f32_16x16x32_f16(*(const h8*)(hp + kgrp*8),      WF2[0], acc2, 0, 0, 0);
    acc2 = __builtin_amdgcn_mfma_f32_16x16x32_f16(*(const h8*)(hp + 32 + kgrp*8), WF2[1], acc2, 0, 0, 0);
    int node0 = t0 + rsub*16 + kgrp*4;
    if (node0 < NPG) {
      uint2 u;
      u.x = packh2(acc2[0], acc2[1]);
      u.y = packh2(acc2[2], acc2[3]);
      *(uint2*)&out[(size_t)g*MTSZ + (nt*16 + l15)*400 + node0] = u;
    }
  }
}

// ---------------- kRead: gbuf += h3T[16 graphs] @ Wc' (split-K, MFMA) --------
__global__ __launch_bounds__(256) void kRead(
    const _Float16* __restrict__ h3, const _Float16* __restrict__ wfc,
    float* __restrict__ gbuf)
{
  const int tid = threadIdx.x, lane = tid & 63, nt = tid >> 6;
  const int l15 = lane & 15, kgrp = lane >> 4;
  const int rt = blockIdx.x & 15, kc = blockIdx.x >> 4;   // 16 row-tiles x 32 k-chunks
  f32x4 acc = {0,0,0,0};
  const _Float16* hp = h3 + (size_t)(rt*16 + l15)*MTSZ;
  for (int ks = 0; ks < 25; ++ks) {
    int kt = kc*25 + ks;
    h8 af = *(const h8*)(hp + kt*32 + kgrp*8);
    h8 bf = *(const h8*)(wfc + (((size_t)kt*4 + nt)*64 + lane)*8);
    acc = __builtin_amdgcn_mfma_f32_16x16x32_f16(af, bf, acc, 0, 0, 0);
  }
  #pragma unroll
  for (int r = 0; r < 4; ++r)
    atomicAdd(&gbuf[(size_t)(rt*16 + kgrp*4 + r)*H + nt*16 + l15], acc[r]);
}

// ---------------- k6: out = (g + bc) @ Wl + bl ----------------
__global__ __launch_bounds__(512) void k6_final(
    const float* __restrict__ gbuf, const float* __restrict__ bc,
    const float* __restrict__ Wl, const float* __restrict__ bl,
    float* __restrict__ out)
{
  int t = threadIdx.x;           // 512 = 256 graphs * 2 outputs
  int gr = t >> 1, c = t & 1;
  float acc = bl[c];
  for (int f = 0; f < H; ++f)
    acc += (gbuf[gr*H + f] + bc[f]) * Wl[f*2 + c];
  out[gr*2 + c] = acc;
}

extern "C" void kernel_launch(void* const* d_in, const int* in_sizes, int n_in,
                              void* d_out, int out_size, void* d_ws, size_t ws_size,
                              hipStream_t stream)
{
  const float* x  = (const float*)d_in[0];
  const int*   ei = (const int*)d_in[1];
  const float* ew = (const float*)d_in[2];
  const float* W1 = (const float*)d_in[3];
  const float* b1 = (const float*)d_in[4];
  const float* W2 = (const float*)d_in[5];
  const float* b2 = (const float*)d_in[6];
  const float* W3 = (const float*)d_in[7];
  const float* b3 = (const float*)d_in[8];
  const float* Wc = (const float*)d_in[9];
  const float* bc = (const float*)d_in[10];
  const float* Wl = (const float*)d_in[11];
  const float* bl = (const float*)d_in[12];
  float* out = (float*)d_out;
  (void)ws_size;

  char* ws = (char*)d_ws;
  size_t o = 0;
  uint2*     ent  = (uint2*)(ws + o);     o += (size_t)G*CPG*8;        // 27.0 MB
  uint32_t*  boff = (uint32_t*)(ws + o);  o += (size_t)G*16*4;         // 16 KB
  _Float16*  mtA  = (_Float16*)(ws + o);  o += (size_t)G*MTSZ*2 + 256; // 13.1 MB
  _Float16*  mtB  = (_Float16*)(ws + o);  o += (size_t)G*MTSZ*2 + 256; // 13.1 MB
  _Float16*  wf   = (_Float16*)(ws + o);  o += (size_t)WF_TOT*2;       // 3.3 MB
  float*     gbuf = (float*)(ws + o);     o += (size_t)G*H*4;          // 64 KB

  (void)hipMemsetAsync(gbuf, 0, (size_t)G*H*4, stream);

  kPack<<<WF_TOT/256, 256, 0, stream>>>(W1, W2, W3, Wc, wf);
  kNorm<<<G, 256, 0, stream>>>(ei, ew, ent, boff);
  kM1<<<dim3(7, G), 256, 0, stream>>>(x, wf, mtA);
  const int aggLds = 32*ATS*4 + 32*HTS*2;   // 53760 + 4608 = 58368 B
  kAgg<1><<<NTILE*G, 512, aggLds, stream>>>(mtA, wf + W2F_OFF, b1, ent, boff, mtB);
  kAgg<1><<<NTILE*G, 512, aggLds, stream>>>(mtB, wf + W3F_OFF, b2, ent, boff, mtA);
  kAgg<0><<<NTILE*G, 512, aggLds, stream>>>(mtA, wf, b3, ent, boff, mtB);
  kRead<<<512, 256, 0, stream>>>(mtB, wf + WCF_OFF, gbuf);
  k6_final<<<1, 512, 0, stream>>>(gbuf, bc, Wl, bl, out);
}

// Round 8
// 290.313 us; speedup vs baseline: 3.1738x; 1.0254x over previous
//
#include <hip/hip_runtime.h>
#include <hip/hip_bf16.h>
#include <stdint.h>

#define G 256
#define NPG 400
#define DEG 32
#define FIN 400
#define H 64
#define NN (G*NPG)        // 102400
#define EE (G*NPG*DEG)    // 3276800
#define EPG (NPG*DEG)     // 12800 edges per graph
#define CPG (EPG+NPG)     // 13200 entries per graph (edges + self loops)
#define NTILE 13          // 32-row dst tiles per graph (12x32 + 16)
#define ATS 420           // A-tile LDS stride (floats)
#define HTS 72            // h-tile LDS stride (halves)
#define MTSZ 25600        // per-graph M^T elems (64*400)

// wf buffer layout (halves)
#define W1F_OFF 0
#define W1F_N   (13*4*64*8)          // 26624
#define W2F_OFF (W1F_OFF + W1F_N)    // 26624
#define W2F_N   (2*4*64*8)           // 4096
#define W3F_OFF (W2F_OFF + W2F_N)    // 30720
#define WCF_OFF (W3F_OFF + W2F_N)    // 34816
#define WCF_N   (800*4*64*8)         // 1638400
#define WF_TOT  (WCF_OFF + WCF_N)    // 1673216

typedef __attribute__((ext_vector_type(8))) _Float16 h8;
typedef __attribute__((ext_vector_type(4))) float f32x4;

static __device__ __forceinline__ unsigned packh2(float a, float b) {
  unsigned short ua = __builtin_bit_cast(unsigned short, (_Float16)a);
  unsigned short ub = __builtin_bit_cast(unsigned short, (_Float16)b);
  return (unsigned)ua | ((unsigned)ub << 16);
}

static __device__ __forceinline__ h8 cvt8(float4 a, float4 b) {
  h8 r;
  r[0] = (_Float16)a.x; r[1] = (_Float16)a.y; r[2] = (_Float16)a.z; r[3] = (_Float16)a.w;
  r[4] = (_Float16)b.x; r[5] = (_Float16)b.y; r[6] = (_Float16)b.z; r[7] = (_Float16)b.w;
  return r;
}

// ---------------- kNorm: degree + normalized entries bucketed by 32-row tile --
// entry.x = (dst_local<<16) | src_local ; entry.y = bits(norm fp32)
__global__ __launch_bounds__(256) void kNorm(
    const int* __restrict__ ei, const float* __restrict__ ew,
    uint2* __restrict__ ent, uint32_t* __restrict__ boff)
{
  __shared__ float deg[NPG];
  __shared__ float dv[NPG];
  __shared__ uint32_t bcnt[NTILE], bpos[NTILE];
  const int g = blockIdx.x, tid = threadIdx.x;
  const int ebase = g*EPG, nbase = g*NPG;
  const int* rowp = ei;          // sources
  const int* colp = ei + EE;     // targets
  if (tid < NTILE) bcnt[tid] = 0u;
  for (int v = tid; v < NPG; v += 256) deg[v] = 1.0f;   // self-loop weight
  __syncthreads();
  for (int e = tid; e < EPG; e += 256) {
    int c = colp[ebase+e] - nbase;
    atomicAdd(&deg[c], ew[ebase+e]);
    atomicAdd(&bcnt[c >> 5], 1u);
  }
  __syncthreads();
  for (int v = tid; v < NPG; v += 256) dv[v] = rsqrtf(deg[v]);
  if (tid == 0) {
    uint32_t s = 0;
    #pragma unroll
    for (int t = 0; t < NTILE; ++t) {
      uint32_t c = bcnt[t] + ((t < 12) ? 32u : 16u);   // + self loops in tile
      bcnt[t] = s; bpos[t] = s; s += c;
    }
  }
  __syncthreads();
  if (tid < NTILE) boff[g*16 + tid] = bcnt[tid];
  if (tid == NTILE) boff[g*16 + NTILE] = (uint32_t)CPG;
  uint2* eb = ent + (size_t)g*CPG;
  for (int e = tid; e < EPG; e += 256) {
    int src = rowp[ebase+e] - nbase;
    int dst = colp[ebase+e] - nbase;
    float nm = dv[src] * ew[ebase+e] * dv[dst];
    uint32_t p = atomicAdd(&bpos[dst >> 5], 1u);
    eb[p] = make_uint2(((unsigned)dst << 16) | (unsigned)src, __float_as_uint(nm));
  }
  for (int v = tid; v < NPG; v += 256) {
    uint32_t p = atomicAdd(&bpos[v >> 5], 1u);
    eb[p] = make_uint2(((unsigned)v << 16) | (unsigned)v, __float_as_uint(dv[v]*dv[v]));
  }
}

// ---------------- kPack: all weights -> fp16 MFMA B-fragment order ----------
// Also zeroes gbuf (replaces the 93us rocclr small-fill in the graph).
__global__ __launch_bounds__(256) void kPack(
    const float* __restrict__ W1, const float* __restrict__ W2,
    const float* __restrict__ W3, const float* __restrict__ Wc,
    _Float16* __restrict__ wf, float* __restrict__ gbuf)
{
  int idx = blockIdx.x*256 + threadIdx.x;
  if (idx < G*H) gbuf[idx] = 0.f;
  if (idx >= WF_TOT) return;
  if (idx < W2F_OFF) {                       // W1: [ks 13][nt 4][lane][j]
    int i = idx;
    int j = i & 7, ln = (i >> 3) & 63, nt = (i >> 9) & 3, ks = i >> 11;
    int k = ks*32 + (ln >> 4)*8 + j, col = nt*16 + (ln & 15);
    wf[idx] = (k < FIN) ? (_Float16)W1[k*H + col] : (_Float16)0.f;
  } else if (idx < W3F_OFF) {                // W2: [ks 2][nt 4][lane][j]
    int i = idx - W2F_OFF;
    int j = i & 7, ln = (i >> 3) & 63, nt = (i >> 9) & 3, ks = i >> 11;
    wf[idx] = (_Float16)W2[(ks*32 + (ln >> 4)*8 + j)*H + nt*16 + (ln & 15)];
  } else if (idx < WCF_OFF) {                // W3
    int i = idx - W3F_OFF;
    int j = i & 7, ln = (i >> 3) & 63, nt = (i >> 9) & 3, ks = i >> 11;
    wf[idx] = (_Float16)W3[(ks*32 + (ln >> 4)*8 + j)*H + nt*16 + (ln & 15)];
  } else {                                   // Wc with k' = feat*400 + node perm
    int i = idx - WCF_OFF;
    int j = i & 7, ln = (i >> 3) & 63, nt = (i >> 9) & 3, kt = i >> 11;
    int kp = kt*32 + (ln >> 4)*8 + j;        // 0..25599
    int node = kp % 400, feat = kp / 400;
    int col = nt*16 + (ln & 15);
    wf[idx] = (_Float16)Wc[((size_t)node*64 + feat)*64 + col];
  }
}

// ---------------- kM1: MT1 = (x @ W1)^T  per-graph [feat][node], fp16 -------
__global__ __launch_bounds__(256, 4) void kM1(
    const float* __restrict__ x, const _Float16* __restrict__ wf,
    _Float16* __restrict__ mt1)
{
  __shared__ _Float16 sh[64*HTS];            // 9216 B out-stage
  const int tid = threadIdx.x, lane = tid & 63, wave = tid >> 6;
  const int l15 = lane & 15, kgrp = lane >> 4;
  const int g = blockIdx.y, b = blockIdx.x;  // b < 7, nodes b*64..b*64+63
  const int node_l = b*64 + wave*16 + l15;
  const int arow = (node_l < NPG) ? node_l : NPG-1;
  const float* xp = x + ((size_t)g*NPG + arow)*FIN;

  h8 af[13];
  #pragma unroll
  for (int ks = 0; ks < 13; ++ks) {
    int kb = ks*32 + kgrp*8;
    if (kb + 8 <= FIN) {
      float4 a0 = *(const float4*)(xp + kb);
      float4 a1 = *(const float4*)(xp + kb + 4);
      af[ks] = cvt8(a0, a1);
    } else {
      h8 z;
      #pragma unroll
      for (int j = 0; j < 8; ++j) z[j] = (_Float16)0.f;
      af[ks] = z;
    }
  }
  f32x4 acc[4] = {{0,0,0,0},{0,0,0,0},{0,0,0,0},{0,0,0,0}};
  for (int nt = 0; nt < 4; ++nt)
    for (int ks = 0; ks < 13; ++ks) {
      h8 bf = *(const h8*)&wf[W1F_OFF + (((size_t)ks*4 + nt)*64 + lane)*8];
      acc[nt] = __builtin_amdgcn_mfma_f32_16x16x32_f16(af[ks], bf, acc[nt], 0, 0, 0);
    }
  // stage [node_local][feat]
  #pragma unroll
  for (int nt = 0; nt < 4; ++nt) {
    int feat = nt*16 + l15;
    #pragma unroll
    for (int r = 0; r < 4; ++r)
      sh[(wave*16 + kgrp*4 + r)*HTS + feat] = (_Float16)acc[nt][r];
  }
  __syncthreads();
  // transposed coalesced store: MT1[g][feat][b*64 + 0..63]
  const unsigned short* shu = (const unsigned short*)sh;
  for (int i = tid; i < 64*16; i += 256) {
    int feat = i >> 4, seg = i & 15;
    int nl = seg*4, gn = b*64 + nl;
    if (gn < NPG) {
      uint2 u;
      u.x = (unsigned)shu[(nl+0)*HTS + feat] | ((unsigned)shu[(nl+1)*HTS + feat] << 16);
      u.y = (unsigned)shu[(nl+2)*HTS + feat] | ((unsigned)shu[(nl+3)*HTS + feat] << 16);
      *(uint2*)&mt1[(size_t)g*MTSZ + feat*400 + gn] = u;
    }
  }
}

// ---------------- kAgg<WMUL>: one 32-row dst tile: scatter + agg MFMA --------
// WMUL=1: + bias + relu + fused next-layer GEMM -> MT_out.  WMUL=0: + bias -> MT-layout out.
template<int WMUL>
__global__ __launch_bounds__(512, 4) void kAgg(
    const _Float16* __restrict__ mtin, const _Float16* __restrict__ wfn,
    const float* __restrict__ bias,
    const uint2* __restrict__ ent, const uint32_t* __restrict__ boff,
    _Float16* __restrict__ out)
{
  extern __shared__ char smem[];
  float* sAT = (float*)smem;                     // 32*420*4 = 53760 B
  _Float16* sh = (_Float16*)(smem + 32*ATS*4);   // 32*72*2  = 4608 B
  const int tid = threadIdx.x, lane = tid & 63, wave = tid >> 6;
  const int l15 = lane & 15, kgrp = lane >> 4;
  const int bid = blockIdx.x;
  const int g = bid & 255, t = bid >> 8;         // same-graph blocks share XCD
  const int t0 = t*32;
  const int rsub = wave & 1, nt = wave >> 1;
  const uint2* eb = ent + (size_t)g*CPG;
  const uint32_t s0 = boff[g*16 + t], s1 = boff[g*16 + t + 1];

  // global prefetches (all independent; overlap with zeroing)
  h8 BF[13];
  const _Float16* mrow = mtin + (size_t)g*MTSZ + (nt*16 + l15)*400;
  #pragma unroll
  for (int ks = 0; ks < 13; ++ks)
    BF[ks] = *(const h8*)(mrow + ks*32 + kgrp*8);
  const float bv = bias[nt*16 + l15];
  h8 WF2[2];
  if (WMUL) {
    WF2[0] = *(const h8*)&wfn[((size_t)(0*4 + nt)*64 + lane)*8];
    WF2[1] = *(const h8*)&wfn[((size_t)(1*4 + nt)*64 + lane)*8];
  }
  const uint32_t e0 = s0 + tid;
  uint2 E0 = make_uint2(0,0), E1 = make_uint2(0,0), E2 = make_uint2(0,0);
  if (e0        < s1) E0 = eb[e0];
  if (e0 + 512  < s1) E1 = eb[e0 + 512];
  if (e0 + 1024 < s1) E2 = eb[e0 + 1024];

  // zero A-tile
  { float4* p = (float4*)sAT;
    for (int i = tid; i < 32*ATS/4; i += 512) p[i] = make_float4(0,0,0,0); }
  __syncthreads();

  // scatter
  if (e0        < s1) atomicAdd(&sAT[((int)(E0.x >> 16) - t0)*ATS + (int)(E0.x & 0xffffu)], __uint_as_float(E0.y));
  if (e0 + 512  < s1) atomicAdd(&sAT[((int)(E1.x >> 16) - t0)*ATS + (int)(E1.x & 0xffffu)], __uint_as_float(E1.y));
  if (e0 + 1024 < s1) atomicAdd(&sAT[((int)(E2.x >> 16) - t0)*ATS + (int)(E2.x & 0xffffu)], __uint_as_float(E2.y));
  for (uint32_t e = e0 + 1536; e < s1; e += 512) {
    uint2 E = eb[e];
    atomicAdd(&sAT[((int)(E.x >> 16) - t0)*ATS + (int)(E.x & 0xffffu)], __uint_as_float(E.y));
  }
  __syncthreads();

  // agg MFMA: rows rsub*16.., cols nt*16..
  f32x4 acc = {0,0,0,0};
  const float* ap = &sAT[(rsub*16 + l15)*ATS];
  #pragma unroll
  for (int ks = 0; ks < 13; ++ks) {
    int kb = ks*32 + kgrp*8;
    float4 a0 = *(const float4*)(ap + kb);
    float4 a1 = *(const float4*)(ap + kb + 4);
    acc = __builtin_amdgcn_mfma_f32_16x16x32_f16(cvt8(a0, a1), BF[ks], acc, 0, 0, 0);
  }

  if (!WMUL) {
    // layer 3: bias only, store MT layout (= h3 transposed k' order)
    int node0 = t0 + rsub*16 + kgrp*4;
    if (node0 < NPG) {
      uint2 u;
      u.x = packh2(acc[0] + bv, acc[1] + bv);
      u.y = packh2(acc[2] + bv, acc[3] + bv);
      *(uint2*)&out[(size_t)g*MTSZ + (nt*16 + l15)*400 + node0] = u;
    }
  } else {
    // bias + relu -> h-tile LDS
    int nl0 = rsub*16 + kgrp*4;
    #pragma unroll
    for (int r = 0; r < 4; ++r)
      sh[(nl0 + r)*HTS + nt*16 + l15] = (_Float16)fmaxf(acc[r] + bv, 0.f);
    __syncthreads();
    // fused next-layer GEMM: M_out-tile = h_tile @ Wn
    f32x4 acc2 = {0,0,0,0};
    const _Float16* hp = &sh[(rsub*16 + l15)*HTS];
    acc2 = __builtin_amdgcn_mfma_f32_16x16x32_f16(*(const h8*)(hp + kgrp*8),      WF2[0], acc2, 0, 0, 0);
    acc2 = __builtin_amdgcn_mfma_f32_16x16x32_f16(*(const h8*)(hp + 32 + kgrp*8), WF2[1], acc2, 0, 0, 0);
    int node0 = t0 + rsub*16 + kgrp*4;
    if (node0 < NPG) {
      uint2 u;
      u.x = packh2(acc2[0], acc2[1]);
      u.y = packh2(acc2[2], acc2[3]);
      *(uint2*)&out[(size_t)g*MTSZ + (nt*16 + l15)*400 + node0] = u;
    }
  }
}

// ---------------- kRead: gbuf += h3T[16 graphs] @ Wc' (split-K, MFMA) --------
__global__ __launch_bounds__(256) void kRead(
    const _Float16* __restrict__ h3, const _Float16* __restrict__ wfc,
    float* __restrict__ gbuf)
{
  const int tid = threadIdx.x, lane = tid & 63, nt = tid >> 6;
  const int l15 = lane & 15, kgrp = lane >> 4;
  const int rt = blockIdx.x & 15, kc = blockIdx.x >> 4;   // 16 row-tiles x 32 k-chunks
  f32x4 acc = {0,0,0,0};
  const _Float16* hp = h3 + (size_t)(rt*16 + l15)*MTSZ;
  for (int ks = 0; ks < 25; ++ks) {
    int kt = kc*25 + ks;
    h8 af = *(const h8*)(hp + kt*32 + kgrp*8);
    h8 bf = *(const h8*)(wfc + (((size_t)kt*4 + nt)*64 + lane)*8);
    acc = __builtin_amdgcn_mfma_f32_16x16x32_f16(af, bf, acc, 0, 0, 0);
  }
  #pragma unroll
  for (int r = 0; r < 4; ++r)
    atomicAdd(&gbuf[(size_t)(rt*16 + kgrp*4 + r)*H + nt*16 + l15], acc[r]);
}

// ---------------- k6: out = (g + bc) @ Wl + bl ----------------
__global__ __launch_bounds__(512) void k6_final(
    const float* __restrict__ gbuf, const float* __restrict__ bc,
    const float* __restrict__ Wl, const float* __restrict__ bl,
    float* __restrict__ out)
{
  int t = threadIdx.x;           // 512 = 256 graphs * 2 outputs
  int gr = t >> 1, c = t & 1;
  float acc = bl[c];
  for (int f = 0; f < H; ++f)
    acc += (gbuf[gr*H + f] + bc[f]) * Wl[f*2 + c];
  out[gr*2 + c] = acc;
}

extern "C" void kernel_launch(void* const* d_in, const int* in_sizes, int n_in,
                              void* d_out, int out_size, void* d_ws, size_t ws_size,
                              hipStream_t stream)
{
  const float* x  = (const float*)d_in[0];
  const int*   ei = (const int*)d_in[1];
  const float* ew = (const float*)d_in[2];
  const float* W1 = (const float*)d_in[3];
  const float* b1 = (const float*)d_in[4];
  const float* W2 = (const float*)d_in[5];
  const float* b2 = (const float*)d_in[6];
  const float* W3 = (const float*)d_in[7];
  const float* b3 = (const float*)d_in[8];
  const float* Wc = (const float*)d_in[9];
  const float* bc = (const float*)d_in[10];
  const float* Wl = (const float*)d_in[11];
  const float* bl = (const float*)d_in[12];
  float* out = (float*)d_out;
  (void)ws_size;

  char* ws = (char*)d_ws;
  size_t o = 0;
  uint2*     ent  = (uint2*)(ws + o);     o += (size_t)G*CPG*8;        // 27.0 MB
  uint32_t*  boff = (uint32_t*)(ws + o);  o += (size_t)G*16*4;         // 16 KB
  _Float16*  mtA  = (_Float16*)(ws + o);  o += (size_t)G*MTSZ*2 + 256; // 13.1 MB
  _Float16*  mtB  = (_Float16*)(ws + o);  o += (size_t)G*MTSZ*2 + 256; // 13.1 MB
  _Float16*  wf   = (_Float16*)(ws + o);  o += (size_t)WF_TOT*2;       // 3.3 MB
  float*     gbuf = (float*)(ws + o);     o += (size_t)G*H*4;          // 64 KB

  kPack<<<(WF_TOT+255)/256, 256, 0, stream>>>(W1, W2, W3, Wc, wf, gbuf);
  kNorm<<<G, 256, 0, stream>>>(ei, ew, ent, boff);
  kM1<<<dim3(7, G), 256, 0, stream>>>(x, wf, mtA);
  const int aggLds = 32*ATS*4 + 32*HTS*2;   // 53760 + 4608 = 58368 B
  kAgg<1><<<NTILE*G, 512, aggLds, stream>>>(mtA, wf + W2F_OFF, b1, ent, boff, mtB);
  kAgg<1><<<NTILE*G, 512, aggLds, stream>>>(mtB, wf + W3F_OFF, b2, ent, boff, mtA);
  kAgg<0><<<NTILE*G, 512, aggLds, stream>>>(mtA, wf, b3, ent, boff, mtB);
  kRead<<<512, 256, 0, stream>>>(mtB, wf + WCF_OFF, gbuf);
  k6_final<<<1, 512, 0, stream>>>(gbuf, bc, Wl, bl, out);
}